// Round 1
// baseline (1012.424 us; speedup 1.0000x reference)
//
#include <hip/hip_runtime.h>

typedef unsigned short u16;
typedef unsigned int u32;
typedef __attribute__((ext_vector_type(4))) float f32x4;
typedef __attribute__((ext_vector_type(8))) short s16x8;

__device__ __forceinline__ u16 f2bf(float f) {
  union { float f; u32 u; } v; v.f = f;
  u32 u = v.u;
  return (u16)((u + 0x7fffu + ((u >> 16) & 1u)) >> 16);
}
__device__ __forceinline__ float bf2f(u16 b) {
  union { u32 u; float f; } v; v.u = ((u32)b) << 16;
  return v.f;
}
__device__ __forceinline__ float bf2f_s(short b) { return bf2f((u16)b); }
__device__ __forceinline__ float sigmoidf(float x) { return 1.0f / (1.0f + __expf(-x)); }

__device__ __forceinline__ void async16(const void* g, void* l) {
  __builtin_amdgcn_global_load_lds(
      (const __attribute__((address_space(1))) u32*)g,
      (__attribute__((address_space(3))) u32*)l, 16, 0, 0);
}

// ---------------------------------------------------------------------------
// prep: A fp32 -> bf16 in ws, and fp32 copy into output slot 1
// ---------------------------------------------------------------------------
__global__ __launch_bounds__(256) void prep_a(
    const float* __restrict__ A, u16* __restrict__ Abf, float* __restrict__ outA)
{
  const long i = ((long)blockIdx.x * 256 + threadIdx.x) * 4;
  float4 v = *(const float4*)(A + i);
  *(float4*)(outA + i) = v;
  ushort4 p;
  p.x = f2bf(v.x); p.y = f2bf(v.y); p.z = f2bf(v.z); p.w = f2bf(v.w);
  *(ushort4*)(Abf + i) = p;
}

// ---------------------------------------------------------------------------
// prep: build WcT [128][WK] bf16: rows 0..63 = (W0+W1)^T, 64..127 = W2^T,
// k = k3*CIN + cin (matches contiguous patch layout), zero pad k >= 3*CIN.
// tw layout: [3][1][3][CIN][64]
// ---------------------------------------------------------------------------
__global__ __launch_bounds__(256) void prep_w(
    const float* __restrict__ tw, u16* __restrict__ WcT, int CIN, int WK)
{
  const int idx = blockIdx.x * 256 + threadIdx.x;
  if (idx >= 128 * WK) return;
  const int c = idx / WK;
  const int k = idx - c * WK;
  const int KR = CIN * 3;
  float v = 0.0f;
  if (k < KR) {
    const int k3 = k / CIN, cin = k - k3 * CIN;
    if (c < 64)
      v = tw[(k3 * CIN + cin) * 64 + c] + tw[(3 * CIN + k3 * CIN + cin) * 64 + c];
    else
      v = tw[(6 * CIN + k3 * CIN + cin) * 64 + (c - 64)];
  }
  WcT[idx] = f2bf(v);
}

// ---------------------------------------------------------------------------
// TB1: Cin=2 temporal block, fp32 VALU. x [16][2048][24][2] fp32.
// Output t1s[(b*22+t)*64+c][n] bf16  (node-contiguous, feeds SP1 B-operand).
// ---------------------------------------------------------------------------
__global__ __launch_bounds__(256) void tb1_kernel(
    const float* __restrict__ x, const float* __restrict__ wt,
    const float* __restrict__ bias, u16* __restrict__ t1)
{
  __shared__ float Wt[6 * 64], Wg[6 * 64], Bt[64], Bg[64];
  const int tid = threadIdx.x;
  for (int i = tid; i < 384; i += 256) {
    Wt[i] = wt[i] + wt[384 + i];
    Wg[i] = wt[768 + i];
  }
  if (tid < 64) { Bt[tid] = bias[tid] + bias[64 + tid]; Bg[tid] = bias[128 + tid]; }
  __syncthreads();
  const int n = blockIdx.x * 256 + tid;
  const int b = blockIdx.y, t = blockIdx.z;
  const float* xp = x + ((long)(b * 2048 + n) * 24 + t) * 2;
  float xv[6];
#pragma unroll
  for (int j = 0; j < 6; j++) xv[j] = xp[j];
  u16* op = t1 + ((long)((b * 22 + t) * 64) << 11) + n;
#pragma unroll 8
  for (int c = 0; c < 64; c++) {
    float tv = Bt[c], gv = Bg[c];
#pragma unroll
    for (int j = 0; j < 6; j++) { tv += xv[j] * Wt[j * 64 + c]; gv += xv[j] * Wg[j * 64 + c]; }
    op[(long)c << 11] = f2bf(fmaxf(tv * sigmoidf(gv), 0.0f));
  }
}

// ---------------------------------------------------------------------------
// Spatial GEMM (NT): C[i,col] = sum_j A[i,j] * X[col, j]
// A [2048][2048] bf16 row-major; X [Ncols][2048] bf16 (j contiguous).
// C [2048][Ncols] bf16. 128x128 tile, BK=64, global_load_lds + XOR swizzle.
// ---------------------------------------------------------------------------
__global__ __launch_bounds__(256, 2) void sp_gemm(
    const u16* __restrict__ A, const u16* __restrict__ X,
    u16* __restrict__ C, int Ncols)
{
  __shared__ u16 ldsA[128 * 64];
  __shared__ u16 ldsB[128 * 64];
  const int lane = threadIdx.x & 63;
  const int w = threadIdx.x >> 6;

  // group swizzle: 128 blocks/group = 16 row-tiles x 8 col-tiles
  const int bid = blockIdx.x;
  const int group = bid >> 7;
  const int loc = bid & 127;
  const int ct = group * 8 + (loc & 7);
  const int rt = loc >> 3;
  const int i0 = rt * 128;
  const int c0 = ct * 128;

  const int wm = w & 1, wn = w >> 1;
  const int lm = lane & 15, q = lane >> 4;

  f32x4 acc[4][4];
#pragma unroll
  for (int a = 0; a < 4; a++)
#pragma unroll
    for (int b2 = 0; b2 < 4; b2++) acc[a][b2] = f32x4{0.f, 0.f, 0.f, 0.f};

  // staging: lane -> (row = lane/8 within 8-row group, phys granule = lane&7)
  // phys granule p holds logical granule p ^ (row&7)
  const int srow = lane >> 3;
  const int sg = (lane & 7) ^ srow;
  const u16* gA = A + ((long)(i0 + w * 32 + srow) << 11) + sg * 8;
  const u16* gB = X + ((long)(c0 + w * 32 + srow) << 11) + sg * 8;
  u16* lA = ldsA + w * 2048;
  u16* lB = ldsB + w * 2048;

  for (int k0 = 0; k0 < 2048; k0 += 64) {
    __syncthreads();
#pragma unroll
    for (int j = 0; j < 4; j++) {
      async16(gA + j * 16384 + k0, lA + j * 512);
      async16(gB + j * 16384 + k0, lB + j * 512);
    }
    __syncthreads();
#pragma unroll
    for (int kk = 0; kk < 2; kk++) {
      const int ph = (kk * 4 + q) ^ (lm & 7);
      s16x8 af[4], bfr[4];
#pragma unroll
      for (int mt = 0; mt < 4; mt++)
        af[mt] = *(const s16x8*)(ldsA + (wm * 64 + mt * 16 + lm) * 64 + ph * 8);
#pragma unroll
      for (int nt = 0; nt < 4; nt++)
        bfr[nt] = *(const s16x8*)(ldsB + (wn * 64 + nt * 16 + lm) * 64 + ph * 8);
#pragma unroll
      for (int mt = 0; mt < 4; mt++)
#pragma unroll
        for (int nt = 0; nt < 4; nt++)
          acc[mt][nt] = __builtin_amdgcn_mfma_f32_16x16x32_bf16(af[mt], bfr[nt], acc[mt][nt], 0, 0, 0);
    }
  }

#pragma unroll
  for (int mt = 0; mt < 4; mt++) {
#pragma unroll
    for (int r = 0; r < 4; r++) {
      const long i = i0 + wm * 64 + mt * 16 + q * 4 + r;
      u16* crow = C + i * Ncols + c0 + wn * 64 + lm;
#pragma unroll
      for (int nt = 0; nt < 4; nt++)
        crow[nt * 16] = f2bf(acc[mt][nt][r]);
    }
  }
}

// ---------------------------------------------------------------------------
// theta + relu: o[row][p] = relu(sum_m lfs[row][m] * th[m][p]), m=64, p=16
// ---------------------------------------------------------------------------
__global__ __launch_bounds__(256) void theta_relu(
    const u16* __restrict__ lfs, const float* __restrict__ th, u16* __restrict__ o)
{
  __shared__ float ths[1024];
  const int tid = threadIdx.x;
  for (int i = tid; i < 1024; i += 256) ths[i] = th[i];
  __syncthreads();
  const long row = (long)blockIdx.x * 16 + (tid >> 4);
  const int p = tid & 15;
  const u16* rp = lfs + row * 64;
  float acc = 0.0f;
#pragma unroll
  for (int m0 = 0; m0 < 64; m0 += 8) {
    s16x8 v = *(const s16x8*)(rp + m0);
#pragma unroll
    for (int j = 0; j < 8; j++) acc += bf2f_s(v[j]) * ths[(m0 + j) * 16 + p];
  }
  o[row * 16 + p] = f2bf(fmaxf(acc, 0.0f));
}

// ---------------------------------------------------------------------------
// Conv temporal block as GEMM. Input [n][16][TIN][CIN] bf16 (patch contiguous).
// WcT [128][WK] bf16 (zero-padded K). pos = (b*TOUT+t)*2048 + n, 128 pos/block.
// D[pos][cout'] via MFMA; epilogue gates (couts 64..127) vs temps (0..63).
// OUTMODE 0: out [n][16][TOUT][64].  OUTMODE 1: out [(b*TOUT+t)*64+c][n]
// (LDS-transposed store, feeds next spatial GEMM).
// ---------------------------------------------------------------------------
template <int CIN, int TIN, int WK, int G, int OUTMODE>
__global__ __launch_bounds__(256, 2) void conv_gemm(
    const u16* __restrict__ in, const u16* __restrict__ WcT,
    const float* __restrict__ bias, u16* __restrict__ out)
{
  static_assert(G * 8 == WK, "granules");
  constexpr int TOUT = TIN - 2;
  constexpr int ROWS = 16 * TIN * CIN;
  __shared__ u16 lds[128 * WK];
  const int lane = threadIdx.x & 63;
  const int w = threadIdx.x >> 6;
  const int lm = lane & 15, q = lane >> 4;
  const int pos0 = blockIdx.x << 7;
  const int n0 = pos0 & 2047;
  const int bt = pos0 >> 11;              // uniform per block (128 | 2048)
  const int b = bt / TOUT, t = bt - b * TOUT;
  const int cb = (b * TIN + t) * CIN;

  // stage 128 patches (row length WK elems = G granules), XOR swizzle
#pragma unroll
  for (int j = 0; j < G / 2; j++) {
    const int Gi = (j * 4 + w) * 64 + lane;
    const int row = Gi / G;
    const int p = Gi - row * G;
    const int l = p ^ (row & 7);
    async16(in + (long)(n0 + row) * ROWS + cb + l * 8, lds + (j * 4 + w) * 512);
  }

  f32x4 acc[2][8];
#pragma unroll
  for (int a = 0; a < 2; a++)
#pragma unroll
    for (int c = 0; c < 8; c++) acc[a][c] = f32x4{0.f, 0.f, 0.f, 0.f};

  __syncthreads();

#pragma unroll
  for (int kk = 0; kk < WK / 32; kk++) {
    const int ph = (kk * 4 + q) ^ (lm & 7);
    s16x8 pf0 = *(const s16x8*)(lds + (w * 32 + lm) * WK + ph * 8);
    s16x8 pf1 = *(const s16x8*)(lds + (w * 32 + 16 + lm) * WK + ph * 8);
#pragma unroll
    for (int nt = 0; nt < 8; nt++) {
      s16x8 wf = *(const s16x8*)(WcT + (nt * 16 + lm) * WK + kk * 32 + q * 8);
      acc[0][nt] = __builtin_amdgcn_mfma_f32_16x16x32_bf16(pf0, wf, acc[0][nt], 0, 0, 0);
      acc[1][nt] = __builtin_amdgcn_mfma_f32_16x16x32_bf16(pf1, wf, acc[1][nt], 0, 0, 0);
    }
  }

  if constexpr (OUTMODE == 1) __syncthreads();  // all patch reads done before LDS reuse

#pragma unroll
  for (int nt = 0; nt < 4; nt++) {
    const int c = nt * 16 + lm;
    const float bsum = bias[c] + bias[64 + c];
    const float bg = bias[128 + c];
#pragma unroll
    for (int mt = 0; mt < 2; mt++) {
#pragma unroll
      for (int r = 0; r < 4; r++) {
        const float temp = acc[mt][nt][r] + bsum;
        const float ga = acc[mt][nt + 4][r] + bg;
        const float res = fmaxf(temp * sigmoidf(ga), 0.0f);
        const int pl = w * 32 + mt * 16 + q * 4 + r;
        if constexpr (OUTMODE == 0) {
          const long n = n0 + pl;
          out[((n * 16 + b) * (long)TOUT + t) * 64 + c] = f2bf(res);
        } else {
          lds[c * 136 + pl] = f2bf(res);
        }
      }
    }
  }
  if constexpr (OUTMODE == 1) {
    __syncthreads();
    const int c2 = threadIdx.x >> 2, seg = threadIdx.x & 3;
    const long rowb = ((long)(bt * 64 + c2) << 11) + n0 + seg * 32;
#pragma unroll
    for (int ii = 0; ii < 4; ii++)
      *(uint4*)(out + rowb + ii * 8) = *(const uint4*)(lds + c2 * 136 + seg * 32 + ii * 8);
  }
}

// ---------------------------------------------------------------------------
// FC: out4[b][n][p] = sum_k out3row[k]*fw[k][p] + fb[p]; row = n*16+b, k=896
// ---------------------------------------------------------------------------
__global__ __launch_bounds__(256) void fc_kernel(
    const u16* __restrict__ o3, const float* __restrict__ fw,
    const float* __restrict__ fb, float* __restrict__ out)
{
  const int tid = threadIdx.x;
  const int r = blockIdx.x * 16 + (tid >> 4);
  const int p = tid & 15;
  const int pc = p < 12 ? p : 11;
  const int n = r >> 4, b = r & 15;
  const u16* rp = o3 + (long)r * 896;
  float acc = 0.0f;
  for (int k0 = 0; k0 < 896; k0 += 8) {
    s16x8 v = *(const s16x8*)(rp + k0);
#pragma unroll
    for (int j = 0; j < 8; j++) acc += bf2f_s(v[j]) * fw[(k0 + j) * 12 + pc];
  }
  if (p < 12) out[((long)b * 2048 + n) * 12 + p] = acc + fb[p];
}

// ---------------------------------------------------------------------------
extern "C" void kernel_launch(void* const* d_in, const int* in_sizes, int n_in,
                              void* d_out, int out_size, void* d_ws, size_t ws_size,
                              hipStream_t stream)
{
  const float* x    = (const float*)d_in[0];
  const float* A    = (const float*)d_in[1];
  const float* tb1w = (const float*)d_in[2];
  const float* tb1b = (const float*)d_in[3];
  const float* th1  = (const float*)d_in[4];
  const float* tb2w = (const float*)d_in[5];
  const float* tb2b = (const float*)d_in[6];
  const float* tb3w = (const float*)d_in[7];
  const float* tb3b = (const float*)d_in[8];
  const float* th2  = (const float*)d_in[9];
  const float* tb4w = (const float*)d_in[10];
  const float* tb4b = (const float*)d_in[11];
  const float* tb5w = (const float*)d_in[12];
  const float* tb5b = (const float*)d_in[13];
  const float* fw   = (const float*)d_in[14];
  const float* fb   = (const float*)d_in[15];
  float* out = (float*)d_out;

  char* ws = (char*)d_ws;
  u16* Abf  = (u16*)(ws + 0);            //  8,388,608 B
  u16* W2   = (u16*)(ws + 8388608);      //     16,384
  u16* W3   = (u16*)(ws + 8404992);      //     49,152
  u16* W4   = (u16*)(ws + 8454144);      //     16,384
  u16* W5   = (u16*)(ws + 8470528);      //     49,152
  u16* bufA = (u16*)(ws + 8519680);      // 92,274,688
  u16* bufB = (u16*)(ws + 100794368);    // 92,274,688  (end 193,069,056)

  prep_a<<<4096, 256, 0, stream>>>(A, Abf, out + 393216);
  prep_w<<<32, 256, 0, stream>>>(tb2w, W2, 16, 64);
  prep_w<<<96, 256, 0, stream>>>(tb3w, W3, 64, 192);
  prep_w<<<32, 256, 0, stream>>>(tb4w, W4, 16, 64);
  prep_w<<<96, 256, 0, stream>>>(tb5w, W5, 64, 192);

  // block 1
  tb1_kernel<<<dim3(8, 16, 22), 256, 0, stream>>>(x, tb1w, tb1b, bufA);
  sp_gemm<<<16 * 176, 256, 0, stream>>>(Abf, bufA, bufB, 22528);
  theta_relu<<<45056, 256, 0, stream>>>(bufB, th1, bufA);
  conv_gemm<16, 22, 64, 8, 0><<<5120, 256, 0, stream>>>(bufA, W2, tb2b, bufB);
  // block 2
  conv_gemm<64, 20, 192, 24, 1><<<4608, 256, 0, stream>>>(bufB, W3, tb3b, bufA);
  sp_gemm<<<16 * 144, 256, 0, stream>>>(Abf, bufA, bufB, 18432);
  theta_relu<<<36864, 256, 0, stream>>>(bufB, th2, bufA);
  conv_gemm<16, 18, 64, 8, 0><<<4096, 256, 0, stream>>>(bufA, W4, tb4b, bufB);
  // tail
  conv_gemm<64, 16, 192, 24, 0><<<3584, 256, 0, stream>>>(bufB, W5, tb5b, bufA);
  fc_kernel<<<2048, 256, 0, stream>>>(bufA, fw, fb, out);
}

// Round 2
// 769.883 us; speedup vs baseline: 1.3150x; 1.3150x over previous
//
#include <hip/hip_runtime.h>

typedef unsigned short u16;
typedef unsigned int u32;
typedef __attribute__((ext_vector_type(4))) float f32x4;
typedef __attribute__((ext_vector_type(8))) short s16x8;

__device__ __forceinline__ u16 f2bf(float f) {
  union { float f; u32 u; } v; v.f = f;
  u32 u = v.u;
  return (u16)((u + 0x7fffu + ((u >> 16) & 1u)) >> 16);
}
__device__ __forceinline__ float bf2f(u16 b) {
  union { u32 u; float f; } v; v.u = ((u32)b) << 16;
  return v.f;
}
__device__ __forceinline__ float bf2f_s(short b) { return bf2f((u16)b); }
__device__ __forceinline__ float sigmoidf(float x) { return 1.0f / (1.0f + __expf(-x)); }

__device__ __forceinline__ void async16(const void* g, void* l) {
  __builtin_amdgcn_global_load_lds(
      (const __attribute__((address_space(1))) u32*)g,
      (__attribute__((address_space(3))) u32*)l, 16, 0, 0);
}

// ---------------------------------------------------------------------------
// prep: A fp32 -> bf16 in ws, and fp32 copy into output slot 1
// ---------------------------------------------------------------------------
__global__ __launch_bounds__(256) void prep_a(
    const float* __restrict__ A, u16* __restrict__ Abf, float* __restrict__ outA)
{
  const long i = ((long)blockIdx.x * 256 + threadIdx.x) * 4;
  float4 v = *(const float4*)(A + i);
  *(float4*)(outA + i) = v;
  ushort4 p;
  p.x = f2bf(v.x); p.y = f2bf(v.y); p.z = f2bf(v.z); p.w = f2bf(v.w);
  *(ushort4*)(Abf + i) = p;
}

// ---------------------------------------------------------------------------
// prep: build WcT [128][WK] bf16: rows 0..63 = (W0+W1)^T, 64..127 = W2^T,
// k = k3*CIN + cin (matches contiguous patch layout), zero pad k >= 3*CIN.
// tw layout: [3][1][3][CIN][64]
// ---------------------------------------------------------------------------
__global__ __launch_bounds__(256) void prep_w(
    const float* __restrict__ tw, u16* __restrict__ WcT, int CIN, int WK)
{
  const int idx = blockIdx.x * 256 + threadIdx.x;
  if (idx >= 128 * WK) return;
  const int c = idx / WK;
  const int k = idx - c * WK;
  const int KR = CIN * 3;
  float v = 0.0f;
  if (k < KR) {
    const int k3 = k / CIN, cin = k - k3 * CIN;
    if (c < 64)
      v = tw[(k3 * CIN + cin) * 64 + c] + tw[(3 * CIN + k3 * CIN + cin) * 64 + c];
    else
      v = tw[(6 * CIN + k3 * CIN + cin) * 64 + (c - 64)];
  }
  WcT[idx] = f2bf(v);
}

// ---------------------------------------------------------------------------
// TB1 + theta1 fused: Cin=2 temporal block, fp32 VALU. x [16][2048][24][2].
// Each thread owns one (n,b,t): computes 64 gated channels in registers,
// multiplies by theta1 (64x16) -> 16 outputs.
// Output U1[(b*22+t)*16+p][n] bf16 (node-contiguous, feeds SP1 B-operand).
// ---------------------------------------------------------------------------
__global__ __launch_bounds__(256) void tb1_kernel(
    const float* __restrict__ x, const float* __restrict__ wt,
    const float* __restrict__ bias, const float* __restrict__ th1,
    u16* __restrict__ U1)
{
  __shared__ float Wt[6 * 64], Wg[6 * 64], Bt[64], Bg[64], TH[1024];
  const int tid = threadIdx.x;
  for (int i = tid; i < 384; i += 256) {
    Wt[i] = wt[i] + wt[384 + i];
    Wg[i] = wt[768 + i];
  }
  for (int i = tid; i < 1024; i += 256) TH[i] = th1[i];
  if (tid < 64) { Bt[tid] = bias[tid] + bias[64 + tid]; Bg[tid] = bias[128 + tid]; }
  __syncthreads();
  const int n = blockIdx.x * 256 + tid;
  const int b = blockIdx.y, t = blockIdx.z;
  const float* xp = x + ((long)(b * 2048 + n) * 24 + t) * 2;
  float xv[6];
#pragma unroll
  for (int j = 0; j < 6; j++) xv[j] = xp[j];
  float res[64];
#pragma unroll 8
  for (int c = 0; c < 64; c++) {
    float tv = Bt[c], gv = Bg[c];
#pragma unroll
    for (int j = 0; j < 6; j++) { tv += xv[j] * Wt[j * 64 + c]; gv += xv[j] * Wg[j * 64 + c]; }
    res[c] = fmaxf(tv * sigmoidf(gv), 0.0f);
  }
  u16* op = U1 + ((long)((b * 22 + t) * 16) << 11) + n;
#pragma unroll 4
  for (int p = 0; p < 16; p++) {
    float a = 0.0f;
#pragma unroll
    for (int m = 0; m < 64; m++) a += res[m] * TH[m * 16 + p];
    op[(long)p << 11] = f2bf(a);
  }
}

// ---------------------------------------------------------------------------
// Spatial GEMM (NT): C[i,col] = sum_j A[i,j] * X[col, j]  (+ optional relu)
// A [2048][2048] bf16 row-major; X [Ncols][2048] bf16 (j contiguous).
// C [2048][Ncols] bf16 row-major. 128x128 tile, BK=64, async LDS, XOR swizzle.
// ---------------------------------------------------------------------------
template <int RELU>
__global__ __launch_bounds__(256, 2) void sp_gemm(
    const u16* __restrict__ A, const u16* __restrict__ X,
    u16* __restrict__ C, int Ncols)
{
  __shared__ u16 ldsA[128 * 64];
  __shared__ u16 ldsB[128 * 64];
  const int lane = threadIdx.x & 63;
  const int w = threadIdx.x >> 6;

  const int ct = blockIdx.x >> 4;
  const int rt = blockIdx.x & 15;
  const int i0 = rt * 128;
  const int c0 = ct * 128;

  const int wm = w & 1, wn = w >> 1;
  const int lm = lane & 15, q = lane >> 4;

  f32x4 acc[4][4];
#pragma unroll
  for (int a = 0; a < 4; a++)
#pragma unroll
    for (int b2 = 0; b2 < 4; b2++) acc[a][b2] = f32x4{0.f, 0.f, 0.f, 0.f};

  const int srow = lane >> 3;
  const int sg = (lane & 7) ^ srow;
  const u16* gA = A + ((long)(i0 + w * 32 + srow) << 11) + sg * 8;
  const u16* gB = X + ((long)(c0 + w * 32 + srow) << 11) + sg * 8;
  u16* lA = ldsA + w * 2048;
  u16* lB = ldsB + w * 2048;

  for (int k0 = 0; k0 < 2048; k0 += 64) {
    __syncthreads();
#pragma unroll
    for (int j = 0; j < 4; j++) {
      async16(gA + j * 16384 + k0, lA + j * 512);
      async16(gB + j * 16384 + k0, lB + j * 512);
    }
    __syncthreads();
#pragma unroll
    for (int kk = 0; kk < 2; kk++) {
      const int ph = (kk * 4 + q) ^ (lm & 7);
      s16x8 af[4], bfr[4];
#pragma unroll
      for (int mt = 0; mt < 4; mt++)
        af[mt] = *(const s16x8*)(ldsA + (wm * 64 + mt * 16 + lm) * 64 + ph * 8);
#pragma unroll
      for (int nt = 0; nt < 4; nt++)
        bfr[nt] = *(const s16x8*)(ldsB + (wn * 64 + nt * 16 + lm) * 64 + ph * 8);
#pragma unroll
      for (int mt = 0; mt < 4; mt++)
#pragma unroll
        for (int nt = 0; nt < 4; nt++)
          acc[mt][nt] = __builtin_amdgcn_mfma_f32_16x16x32_bf16(af[mt], bfr[nt], acc[mt][nt], 0, 0, 0);
    }
  }

#pragma unroll
  for (int mt = 0; mt < 4; mt++) {
#pragma unroll
    for (int r = 0; r < 4; r++) {
      const long i = i0 + wm * 64 + mt * 16 + q * 4 + r;
      u16* crow = C + i * Ncols + c0 + wn * 64 + lm;
#pragma unroll
      for (int nt = 0; nt < 4; nt++) {
        float v = acc[mt][nt][r];
        if (RELU) v = fmaxf(v, 0.0f);
        crow[nt * 16] = f2bf(v);
      }
    }
  }
}

// ---------------------------------------------------------------------------
// theta2 transform + transpose: in [n][16][TOUT][64] bf16 ->
// U2[(b*TOUT+t)*16+p][n] = sum_m in[n][b][t][m] * th[m][p]   (no relu here)
// One block: 128 n x one (b,t). grid = (2048/128) * 16 * TOUT.
// ---------------------------------------------------------------------------
__global__ __launch_bounds__(256) void theta_t(
    const u16* __restrict__ in, const float* __restrict__ th,
    u16* __restrict__ outp, int TOUT)
{
  __shared__ float ths[1024];
  __shared__ u16 tr[16 * 136];
  const int tid = threadIdx.x;
  for (int i = tid; i < 1024; i += 256) ths[i] = th[i];
  __syncthreads();
  const int nb = blockIdx.x & 15;
  const int bt = blockIdx.x >> 4;
  const int b = bt / TOUT, t = bt - b * TOUT;
  const int n0 = nb << 7;
  const int ngrp = tid >> 4, p = tid & 15;
#pragma unroll
  for (int k = 0; k < 8; k++) {
    const int n = n0 + ngrp * 8 + k;
    const u16* rp = in + ((long)((n * 16 + b) * TOUT + t) << 6);
    float acc = 0.0f;
#pragma unroll
    for (int m0 = 0; m0 < 64; m0 += 8) {
      s16x8 v = *(const s16x8*)(rp + m0);
#pragma unroll
      for (int j = 0; j < 8; j++) acc += bf2f_s(v[j]) * ths[(m0 + j) * 16 + p];
    }
    tr[p * 136 + ngrp * 8 + k] = f2bf(acc);
  }
  __syncthreads();
  const int p3 = tid >> 4, seg = tid & 15;
  *(uint4*)(outp + ((long)(bt * 16 + p3) << 11) + n0 + seg * 8) =
      *(const uint4*)(tr + p3 * 136 + seg * 8);
}

// ---------------------------------------------------------------------------
// Conv temporal block as GEMM. Input [n][16][TIN][CIN] bf16 (patch contiguous).
// WcT [128][WK] bf16 (zero-padded K). pos = (b*TOUT+t)*2048 + n, 128 pos/block.
// Epilogue gates (couts 64..127) vs temps (0..63). Output [n][16][TOUT][64].
// ---------------------------------------------------------------------------
template <int CIN, int TIN, int WK, int G>
__global__ __launch_bounds__(256, 2) void conv_gemm(
    const u16* __restrict__ in, const u16* __restrict__ WcT,
    const float* __restrict__ bias, u16* __restrict__ out)
{
  static_assert(G * 8 == WK, "granules");
  constexpr int TOUT = TIN - 2;
  constexpr int ROWS = 16 * TIN * CIN;
  __shared__ u16 lds[128 * WK];
  const int lane = threadIdx.x & 63;
  const int w = threadIdx.x >> 6;
  const int lm = lane & 15, q = lane >> 4;
  const int pos0 = blockIdx.x << 7;
  const int n0 = pos0 & 2047;
  const int bt = pos0 >> 11;              // uniform per block (128 | 2048)
  const int b = bt / TOUT, t = bt - b * TOUT;
  const int cb = (b * TIN + t) * CIN;

#pragma unroll
  for (int j = 0; j < G / 2; j++) {
    const int Gi = (j * 4 + w) * 64 + lane;
    const int row = Gi / G;
    const int p = Gi - row * G;
    const int l = p ^ (row & 7);
    async16(in + (long)(n0 + row) * ROWS + cb + l * 8, lds + (j * 4 + w) * 512);
  }

  f32x4 acc[2][8];
#pragma unroll
  for (int a = 0; a < 2; a++)
#pragma unroll
    for (int c = 0; c < 8; c++) acc[a][c] = f32x4{0.f, 0.f, 0.f, 0.f};

  __syncthreads();

#pragma unroll
  for (int kk = 0; kk < WK / 32; kk++) {
    const int ph = (kk * 4 + q) ^ (lm & 7);
    s16x8 pf0 = *(const s16x8*)(lds + (w * 32 + lm) * WK + ph * 8);
    s16x8 pf1 = *(const s16x8*)(lds + (w * 32 + 16 + lm) * WK + ph * 8);
#pragma unroll
    for (int nt = 0; nt < 8; nt++) {
      s16x8 wf = *(const s16x8*)(WcT + (nt * 16 + lm) * WK + kk * 32 + q * 8);
      acc[0][nt] = __builtin_amdgcn_mfma_f32_16x16x32_bf16(pf0, wf, acc[0][nt], 0, 0, 0);
      acc[1][nt] = __builtin_amdgcn_mfma_f32_16x16x32_bf16(pf1, wf, acc[1][nt], 0, 0, 0);
    }
  }

#pragma unroll
  for (int nt = 0; nt < 4; nt++) {
    const int c = nt * 16 + lm;
    const float bsum = bias[c] + bias[64 + c];
    const float bg = bias[128 + c];
#pragma unroll
    for (int mt = 0; mt < 2; mt++) {
#pragma unroll
      for (int r = 0; r < 4; r++) {
        const float temp = acc[mt][nt][r] + bsum;
        const float ga = acc[mt][nt + 4][r] + bg;
        const float res = fmaxf(temp * sigmoidf(ga), 0.0f);
        const int pl = w * 32 + mt * 16 + q * 4 + r;
        const long n = n0 + pl;
        out[((n * 16 + b) * (long)TOUT + t) * 64 + c] = f2bf(res);
      }
    }
  }
}

// ---------------------------------------------------------------------------
// FC: out4[b][n][p] = sum_k out3row[k]*fw[k][p] + fb[p]; row = n*16+b, k=896
// ---------------------------------------------------------------------------
__global__ __launch_bounds__(256) void fc_kernel(
    const u16* __restrict__ o3, const float* __restrict__ fw,
    const float* __restrict__ fb, float* __restrict__ out)
{
  const int tid = threadIdx.x;
  const int r = blockIdx.x * 16 + (tid >> 4);
  const int p = tid & 15;
  const int pc = p < 12 ? p : 11;
  const int n = r >> 4, b = r & 15;
  const u16* rp = o3 + (long)r * 896;
  float acc = 0.0f;
  for (int k0 = 0; k0 < 896; k0 += 8) {
    s16x8 v = *(const s16x8*)(rp + k0);
#pragma unroll
    for (int j = 0; j < 8; j++) acc += bf2f_s(v[j]) * fw[(k0 + j) * 12 + pc];
  }
  if (p < 12) out[((long)b * 2048 + n) * 12 + p] = acc + fb[p];
}

// ---------------------------------------------------------------------------
extern "C" void kernel_launch(void* const* d_in, const int* in_sizes, int n_in,
                              void* d_out, int out_size, void* d_ws, size_t ws_size,
                              hipStream_t stream)
{
  const float* x    = (const float*)d_in[0];
  const float* A    = (const float*)d_in[1];
  const float* tb1w = (const float*)d_in[2];
  const float* tb1b = (const float*)d_in[3];
  const float* th1  = (const float*)d_in[4];
  const float* tb2w = (const float*)d_in[5];
  const float* tb2b = (const float*)d_in[6];
  const float* tb3w = (const float*)d_in[7];
  const float* tb3b = (const float*)d_in[8];
  const float* th2  = (const float*)d_in[9];
  const float* tb4w = (const float*)d_in[10];
  const float* tb4b = (const float*)d_in[11];
  const float* tb5w = (const float*)d_in[12];
  const float* tb5b = (const float*)d_in[13];
  const float* fw   = (const float*)d_in[14];
  const float* fb   = (const float*)d_in[15];
  float* out = (float*)d_out;

  char* ws = (char*)d_ws;
  u16* Abf  = (u16*)(ws + 0);            //  8,388,608 B
  u16* W2   = (u16*)(ws + 8388608);      //     16,384
  u16* W3   = (u16*)(ws + 8404992);      //     49,152
  u16* W4   = (u16*)(ws + 8454144);      //     16,384
  u16* W5   = (u16*)(ws + 8470528);      //     49,152
  u16* bufA = (u16*)(ws + 8519680);      // 92,274,688
  u16* bufB = (u16*)(ws + 100794368);    // 92,274,688  (end 193,069,056)

  prep_a<<<4096, 256, 0, stream>>>(A, Abf, out + 393216);
  prep_w<<<32, 256, 0, stream>>>(tb2w, W2, 16, 64);
  prep_w<<<96, 256, 0, stream>>>(tb3w, W3, 64, 192);
  prep_w<<<32, 256, 0, stream>>>(tb4w, W4, 16, 64);
  prep_w<<<96, 256, 0, stream>>>(tb5w, W5, 64, 192);

  // ---- block 1:  t = TB1(x); U1 = t*th1; t2 = relu(A*U1); TB2(t2)
  tb1_kernel<<<dim3(8, 16, 22), 256, 0, stream>>>(x, tb1w, tb1b, th1, bufA);
  sp_gemm<1><<<44 * 16, 256, 0, stream>>>(Abf, bufA, bufB, 5632);     // -> [n][16][22][16]
  conv_gemm<16, 22, 64, 8><<<5120, 256, 0, stream>>>(bufB, W2, tb2b, bufA);  // -> [n][16][20][64]
  // ---- block 2:  t = TB3(out1); U2 = t*th2; t2 = relu(A*U2); TB4(t2)
  conv_gemm<64, 20, 192, 24><<<4608, 256, 0, stream>>>(bufA, W3, tb3b, bufB); // -> [n][16][18][64]
  theta_t<<<4608, 256, 0, stream>>>(bufB, th2, bufA, 18);             // -> U2 [(b,t,p)][n]
  sp_gemm<1><<<36 * 16, 256, 0, stream>>>(Abf, bufA, bufB, 4608);     // -> [n][16][18][16]
  conv_gemm<16, 18, 64, 8><<<4096, 256, 0, stream>>>(bufB, W4, tb4b, bufA);  // -> [n][16][16][64]
  // ---- tail
  conv_gemm<64, 16, 192, 24><<<3584, 256, 0, stream>>>(bufA, W5, tb5b, bufB); // -> [n][16][14][64]
  fc_kernel<<<2048, 256, 0, stream>>>(bufB, fw, fb, out);
}

// Round 3
// 635.072 us; speedup vs baseline: 1.5942x; 1.2123x over previous
//
#include <hip/hip_runtime.h>

typedef unsigned short u16;
typedef unsigned int u32;
typedef __attribute__((ext_vector_type(4))) float f32x4;
typedef __attribute__((ext_vector_type(8))) short s16x8;

__device__ __forceinline__ u16 f2bf(float f) {
  union { float f; u32 u; } v; v.f = f;
  u32 u = v.u;
  return (u16)((u + 0x7fffu + ((u >> 16) & 1u)) >> 16);
}
__device__ __forceinline__ float bf2f(u16 b) {
  union { u32 u; float f; } v; v.u = ((u32)b) << 16;
  return v.f;
}
__device__ __forceinline__ float bf2f_s(short b) { return bf2f((u16)b); }
__device__ __forceinline__ float sigmoidf(float x) { return 1.0f / (1.0f + __expf(-x)); }

__device__ __forceinline__ void async16(const void* g, void* l) {
  __builtin_amdgcn_global_load_lds(
      (const __attribute__((address_space(1))) u32*)g,
      (__attribute__((address_space(3))) u32*)l, 16, 0, 0);
}

// ---------------------------------------------------------------------------
// prep: A fp32 -> bf16 in ws, and fp32 copy into output slot 1
// ---------------------------------------------------------------------------
__global__ __launch_bounds__(256) void prep_a(
    const float* __restrict__ A, u16* __restrict__ Abf, float* __restrict__ outA)
{
  const long i = ((long)blockIdx.x * 256 + threadIdx.x) * 4;
  float4 v = *(const float4*)(A + i);
  *(float4*)(outA + i) = v;
  ushort4 p;
  p.x = f2bf(v.x); p.y = f2bf(v.y); p.z = f2bf(v.z); p.w = f2bf(v.w);
  *(ushort4*)(Abf + i) = p;
}

// ---------------------------------------------------------------------------
// prep: build WcT [128][WK] bf16: rows 0..63 = (W0+W1)^T, 64..127 = W2^T,
// k = k3*CIN + cin (matches contiguous patch layout), zero pad k >= 3*CIN.
// tw layout: [3][1][3][CIN][64]
// ---------------------------------------------------------------------------
__global__ __launch_bounds__(256) void prep_w(
    const float* __restrict__ tw, u16* __restrict__ WcT, int CIN, int WK)
{
  const int idx = blockIdx.x * 256 + threadIdx.x;
  if (idx >= 128 * WK) return;
  const int c = idx / WK;
  const int k = idx - c * WK;
  const int KR = CIN * 3;
  float v = 0.0f;
  if (k < KR) {
    const int k3 = k / CIN, cin = k - k3 * CIN;
    if (c < 64)
      v = tw[(k3 * CIN + cin) * 64 + c] + tw[(3 * CIN + k3 * CIN + cin) * 64 + c];
    else
      v = tw[(6 * CIN + k3 * CIN + cin) * 64 + (c - 64)];
  }
  WcT[idx] = f2bf(v);
}

// ---------------------------------------------------------------------------
// TB1 + theta1 fused: Cin=2 temporal block, fp32 VALU. x [16][2048][24][2].
// Output U1[(b*22+t)*16+p][n] bf16 (node-contiguous, feeds SP1 B-operand).
// ---------------------------------------------------------------------------
__global__ __launch_bounds__(256) void tb1_kernel(
    const float* __restrict__ x, const float* __restrict__ wt,
    const float* __restrict__ bias, const float* __restrict__ th1,
    u16* __restrict__ U1)
{
  __shared__ float Wt[6 * 64], Wg[6 * 64], Bt[64], Bg[64], TH[1024];
  const int tid = threadIdx.x;
  for (int i = tid; i < 384; i += 256) {
    Wt[i] = wt[i] + wt[384 + i];
    Wg[i] = wt[768 + i];
  }
  for (int i = tid; i < 1024; i += 256) TH[i] = th1[i];
  if (tid < 64) { Bt[tid] = bias[tid] + bias[64 + tid]; Bg[tid] = bias[128 + tid]; }
  __syncthreads();
  const int n = blockIdx.x * 256 + tid;
  const int b = blockIdx.y, t = blockIdx.z;
  const float* xp = x + ((long)(b * 2048 + n) * 24 + t) * 2;
  float xv[6];
#pragma unroll
  for (int j = 0; j < 6; j++) xv[j] = xp[j];
  float res[64];
#pragma unroll 8
  for (int c = 0; c < 64; c++) {
    float tv = Bt[c], gv = Bg[c];
#pragma unroll
    for (int j = 0; j < 6; j++) { tv += xv[j] * Wt[j * 64 + c]; gv += xv[j] * Wg[j * 64 + c]; }
    res[c] = fmaxf(tv * sigmoidf(gv), 0.0f);
  }
  u16* op = U1 + ((long)((b * 22 + t) * 16) << 11) + n;
#pragma unroll 4
  for (int p = 0; p < 16; p++) {
    float a = 0.0f;
#pragma unroll
    for (int m = 0; m < 64; m++) a += res[m] * TH[m * 16 + p];
    op[(long)p << 11] = f2bf(a);
  }
}

// ---------------------------------------------------------------------------
// Spatial GEMM (NT): C[i,col] = sum_j A[i,j] * X[col, j]  (+ optional relu)
// A [2048][2048] bf16 row-major; X [Ncols][2048] bf16 (j contiguous).
// C [2048][Ncols] bf16 row-major. 128x128 tile, BK=64, async LDS, XOR swizzle.
// ---------------------------------------------------------------------------
template <int RELU>
__global__ __launch_bounds__(256, 2) void sp_gemm(
    const u16* __restrict__ A, const u16* __restrict__ X,
    u16* __restrict__ C, int Ncols)
{
  __shared__ u16 ldsA[128 * 64];
  __shared__ u16 ldsB[128 * 64];
  const int lane = threadIdx.x & 63;
  const int w = threadIdx.x >> 6;

  const int ct = blockIdx.x >> 4;
  const int rt = blockIdx.x & 15;
  const int i0 = rt * 128;
  const int c0 = ct * 128;

  const int wm = w & 1, wn = w >> 1;
  const int lm = lane & 15, q = lane >> 4;

  f32x4 acc[4][4];
#pragma unroll
  for (int a = 0; a < 4; a++)
#pragma unroll
    for (int b2 = 0; b2 < 4; b2++) acc[a][b2] = f32x4{0.f, 0.f, 0.f, 0.f};

  const int srow = lane >> 3;
  const int sg = (lane & 7) ^ srow;
  const u16* gA = A + ((long)(i0 + w * 32 + srow) << 11) + sg * 8;
  const u16* gB = X + ((long)(c0 + w * 32 + srow) << 11) + sg * 8;
  u16* lA = ldsA + w * 2048;
  u16* lB = ldsB + w * 2048;

  for (int k0 = 0; k0 < 2048; k0 += 64) {
    __syncthreads();
#pragma unroll
    for (int j = 0; j < 4; j++) {
      async16(gA + j * 16384 + k0, lA + j * 512);
      async16(gB + j * 16384 + k0, lB + j * 512);
    }
    __syncthreads();
#pragma unroll
    for (int kk = 0; kk < 2; kk++) {
      const int ph = (kk * 4 + q) ^ (lm & 7);
      s16x8 af[4], bfr[4];
#pragma unroll
      for (int mt = 0; mt < 4; mt++)
        af[mt] = *(const s16x8*)(ldsA + (wm * 64 + mt * 16 + lm) * 64 + ph * 8);
#pragma unroll
      for (int nt = 0; nt < 4; nt++)
        bfr[nt] = *(const s16x8*)(ldsB + (wn * 64 + nt * 16 + lm) * 64 + ph * 8);
#pragma unroll
      for (int mt = 0; mt < 4; mt++)
#pragma unroll
        for (int nt = 0; nt < 4; nt++)
          acc[mt][nt] = __builtin_amdgcn_mfma_f32_16x16x32_bf16(af[mt], bfr[nt], acc[mt][nt], 0, 0, 0);
    }
  }

#pragma unroll
  for (int mt = 0; mt < 4; mt++) {
#pragma unroll
    for (int r = 0; r < 4; r++) {
      const long i = i0 + wm * 64 + mt * 16 + q * 4 + r;
      u16* crow = C + i * Ncols + c0 + wn * 64 + lm;
#pragma unroll
      for (int nt = 0; nt < 4; nt++) {
        float v = acc[mt][nt][r];
        if (RELU) v = fmaxf(v, 0.0f);
        crow[nt * 16] = f2bf(v);
      }
    }
  }
}

// ---------------------------------------------------------------------------
// theta2 transform + transpose: in [n][16][TOUT][64] bf16 ->
// U2[(b*TOUT+t)*16+p][n] = sum_m in[n][b][t][m] * th[m][p]   (no relu here)
// ---------------------------------------------------------------------------
__global__ __launch_bounds__(256) void theta_t(
    const u16* __restrict__ in, const float* __restrict__ th,
    u16* __restrict__ outp, int TOUT)
{
  __shared__ float ths[1024];
  __shared__ u16 tr[16 * 136];
  const int tid = threadIdx.x;
  for (int i = tid; i < 1024; i += 256) ths[i] = th[i];
  __syncthreads();
  const int nb = blockIdx.x & 15;
  const int bt = blockIdx.x >> 4;
  const int b = bt / TOUT, t = bt - b * TOUT;
  const int n0 = nb << 7;
  const int ngrp = tid >> 4, p = tid & 15;
#pragma unroll
  for (int k = 0; k < 8; k++) {
    const int n = n0 + ngrp * 8 + k;
    const u16* rp = in + ((long)((n * 16 + b) * TOUT + t) << 6);
    float acc = 0.0f;
#pragma unroll
    for (int m0 = 0; m0 < 64; m0 += 8) {
      s16x8 v = *(const s16x8*)(rp + m0);
#pragma unroll
      for (int j = 0; j < 8; j++) acc += bf2f_s(v[j]) * ths[(m0 + j) * 16 + p];
    }
    tr[p * 136 + ngrp * 8 + k] = f2bf(acc);
  }
  __syncthreads();
  const int p3 = tid >> 4, seg = tid & 15;
  *(uint4*)(outp + ((long)(bt * 16 + p3) << 11) + n0 + seg * 8) =
      *(const uint4*)(tr + p3 * 136 + seg * 8);
}

// ---------------------------------------------------------------------------
// Conv temporal block as GEMM, register-resident weights.
// Input [n][16][TIN][CIN] bf16 (patch contiguous). WcT [128][WK] bf16.
// Each block: 128 positions (one (b,t), 128 n). Wave wn computes ALL 128 pos
// x 32 couts: temps [wn*16,wn*16+16) and gates [64+wn*16,..). Weight frags
// (2 x WK/32 s16x8) live in registers, loaded while patch staging in flight.
// Inner loop: per kk, 8 ds_read_b128 + 16 MFMA, no global traffic.
// Epilogue: gate+relu in regs -> LDS (stride 72) -> coalesced 128B row stores.
// Output [n][16][TOUT][64].
// ---------------------------------------------------------------------------
template <int CIN, int TIN, int MINW>
__global__ __launch_bounds__(256, MINW) void conv_gemm(
    const u16* __restrict__ in, const u16* __restrict__ WcT,
    const float* __restrict__ bias, u16* __restrict__ out)
{
  constexpr int WK = (CIN == 64) ? 192 : 64;   // padded K
  constexpr int G = WK / 8;                    // granules per row
  constexpr int KI = WK / 32;                  // kk iterations
  constexpr int TOUT = TIN - 2;
  constexpr int ROWS = 16 * TIN * CIN;
  constexpr int LDSE = (128 * WK > 128 * 72) ? 128 * WK : 128 * 72;
  __shared__ u16 lds[LDSE];

  const int tid = threadIdx.x;
  const int lane = tid & 63;
  const int w = tid >> 6;                      // wave id = cout group
  const int lm = lane & 15, q = lane >> 4;
  const int pos0 = blockIdx.x << 7;
  const int n0 = pos0 & 2047;
  const int bt = pos0 >> 11;                   // uniform per block
  const int b = bt / TOUT, t = bt - b * TOUT;
  const int cb = (b * TIN + t) * CIN;

  // stage 128 patch rows (WK elems each), XOR-swizzled granules
#pragma unroll
  for (int j = 0; j < G / 2; j++) {
    const int Gi = (j * 4 + w) * 64 + lane;
    const int row = Gi / G;
    const int p = Gi - row * G;
    const int l = p ^ (row & 7);
    async16(in + (long)(n0 + row) * ROWS + cb + l * 8, lds + (j * 4 + w) * 512);
  }

  // weight fragments -> registers (overlaps staging; L2-resident after 1st use)
  s16x8 wf[2][KI];
  {
    const u16* wp = WcT + (w * 16 + lm) * WK + q * 8;
#pragma unroll
    for (int kk = 0; kk < KI; kk++) {
      wf[0][kk] = *(const s16x8*)(wp + kk * 32);            // temp couts
      wf[1][kk] = *(const s16x8*)(wp + 64 * WK + kk * 32);  // gate couts
    }
  }

  f32x4 acc[8][2];
#pragma unroll
  for (int m = 0; m < 8; m++) {
    acc[m][0] = f32x4{0.f, 0.f, 0.f, 0.f};
    acc[m][1] = f32x4{0.f, 0.f, 0.f, 0.f};
  }

  __syncthreads();

#pragma unroll
  for (int kk = 0; kk < KI; kk++) {
    const int ph = (kk * 4 + q) ^ (lm & 7);
#pragma unroll
    for (int mt = 0; mt < 8; mt++) {
      s16x8 pf = *(const s16x8*)(lds + (mt * 16 + lm) * WK + ph * 8);
      acc[mt][0] = __builtin_amdgcn_mfma_f32_16x16x32_bf16(pf, wf[0][kk], acc[mt][0], 0, 0, 0);
      acc[mt][1] = __builtin_amdgcn_mfma_f32_16x16x32_bf16(pf, wf[1][kk], acc[mt][1], 0, 0, 0);
    }
  }

  __syncthreads();  // all patch reads done; reuse LDS for result

  const int c = w * 16 + lm;                   // temp cout this thread owns
  const float bsum = bias[c] + bias[64 + c];
  const float bg = bias[128 + c];
#pragma unroll
  for (int mt = 0; mt < 8; mt++) {
#pragma unroll
    for (int r = 0; r < 4; r++) {
      const int pos = mt * 16 + q * 4 + r;
      const float temp = acc[mt][0][r] + bsum;
      const float ga = acc[mt][1][r] + bg;
      lds[pos * 72 + c] = f2bf(fmaxf(temp * sigmoidf(ga), 0.0f));
    }
  }
  __syncthreads();

  const int pos2 = tid >> 1, half = tid & 1;
  u16* orow = out + ((((long)(n0 + pos2) * 16 + b) * TOUT + t) << 6) + half * 32;
#pragma unroll
  for (int i = 0; i < 4; i++)
    *(uint4*)(orow + i * 8) = *(const uint4*)(lds + pos2 * 72 + half * 32 + i * 8);
}

// ---------------------------------------------------------------------------
// FC: out4[b][n][p] = sum_k out3row[k]*fw[k][p] + fb[p]; row = n*16+b, k=896
// ---------------------------------------------------------------------------
__global__ __launch_bounds__(256) void fc_kernel(
    const u16* __restrict__ o3, const float* __restrict__ fw,
    const float* __restrict__ fb, float* __restrict__ out)
{
  const int tid = threadIdx.x;
  const int r = blockIdx.x * 16 + (tid >> 4);
  const int p = tid & 15;
  const int pc = p < 12 ? p : 11;
  const int n = r >> 4, b = r & 15;
  const u16* rp = o3 + (long)r * 896;
  float acc = 0.0f;
  for (int k0 = 0; k0 < 896; k0 += 8) {
    s16x8 v = *(const s16x8*)(rp + k0);
#pragma unroll
    for (int j = 0; j < 8; j++) acc += bf2f_s(v[j]) * fw[(k0 + j) * 12 + pc];
  }
  if (p < 12) out[((long)b * 2048 + n) * 12 + p] = acc + fb[p];
}

// ---------------------------------------------------------------------------
extern "C" void kernel_launch(void* const* d_in, const int* in_sizes, int n_in,
                              void* d_out, int out_size, void* d_ws, size_t ws_size,
                              hipStream_t stream)
{
  const float* x    = (const float*)d_in[0];
  const float* A    = (const float*)d_in[1];
  const float* tb1w = (const float*)d_in[2];
  const float* tb1b = (const float*)d_in[3];
  const float* th1  = (const float*)d_in[4];
  const float* tb2w = (const float*)d_in[5];
  const float* tb2b = (const float*)d_in[6];
  const float* tb3w = (const float*)d_in[7];
  const float* tb3b = (const float*)d_in[8];
  const float* th2  = (const float*)d_in[9];
  const float* tb4w = (const float*)d_in[10];
  const float* tb4b = (const float*)d_in[11];
  const float* tb5w = (const float*)d_in[12];
  const float* tb5b = (const float*)d_in[13];
  const float* fw   = (const float*)d_in[14];
  const float* fb   = (const float*)d_in[15];
  float* out = (float*)d_out;

  char* ws = (char*)d_ws;
  u16* Abf  = (u16*)(ws + 0);            //  8,388,608 B
  u16* W2   = (u16*)(ws + 8388608);      //     16,384
  u16* W3   = (u16*)(ws + 8404992);      //     49,152
  u16* W4   = (u16*)(ws + 8454144);      //     16,384
  u16* W5   = (u16*)(ws + 8470528);      //     49,152
  u16* bufA = (u16*)(ws + 8519680);      // 92,274,688
  u16* bufB = (u16*)(ws + 100794368);    // 92,274,688  (end 193,069,056)

  prep_a<<<4096, 256, 0, stream>>>(A, Abf, out + 393216);
  prep_w<<<32, 256, 0, stream>>>(tb2w, W2, 16, 64);
  prep_w<<<96, 256, 0, stream>>>(tb3w, W3, 64, 192);
  prep_w<<<32, 256, 0, stream>>>(tb4w, W4, 16, 64);
  prep_w<<<96, 256, 0, stream>>>(tb5w, W5, 64, 192);

  // ---- block 1:  t = TB1(x); U1 = t*th1; t2 = relu(A*U1); TB2(t2)
  tb1_kernel<<<dim3(8, 16, 22), 256, 0, stream>>>(x, tb1w, tb1b, th1, bufA);
  sp_gemm<1><<<44 * 16, 256, 0, stream>>>(Abf, bufA, bufB, 5632);         // -> [(b,t,p)][n] rows as cols
  conv_gemm<16, 22, 3><<<5120, 256, 0, stream>>>(bufB, W2, tb2b, bufA);   // -> [n][16][20][64]
  // ---- block 2:  t = TB3(out1); U2 = t*th2; t2 = relu(A*U2); TB4(t2)
  conv_gemm<64, 20, 2><<<4608, 256, 0, stream>>>(bufA, W3, tb3b, bufB);   // -> [n][16][18][64]
  theta_t<<<4608, 256, 0, stream>>>(bufB, th2, bufA, 18);                 // -> U2 [(b,t,p)][n]
  sp_gemm<1><<<36 * 16, 256, 0, stream>>>(Abf, bufA, bufB, 4608);
  conv_gemm<16, 18, 3><<<4096, 256, 0, stream>>>(bufB, W4, tb4b, bufA);   // -> [n][16][16][64]
  // ---- tail
  conv_gemm<64, 16, 2><<<3584, 256, 0, stream>>>(bufA, W5, tb5b, bufB);   // -> [n][16][14][64]
  fc_kernel<<<2048, 256, 0, stream>>>(bufB, fw, fb, out);
}

// Round 4
// 538.964 us; speedup vs baseline: 1.8785x; 1.1783x over previous
//
#include <hip/hip_runtime.h>

typedef unsigned short u16;
typedef unsigned int u32;
typedef __attribute__((ext_vector_type(4))) float f32x4;
typedef __attribute__((ext_vector_type(8))) short s16x8;

__device__ __forceinline__ u16 f2bf(float f) {
  union { float f; u32 u; } v; v.f = f;
  u32 u = v.u;
  return (u16)((u + 0x7fffu + ((u >> 16) & 1u)) >> 16);
}
__device__ __forceinline__ float bf2f(u16 b) {
  union { u32 u; float f; } v; v.u = ((u32)b) << 16;
  return v.f;
}
__device__ __forceinline__ float bf2f_s(short b) { return bf2f((u16)b); }
__device__ __forceinline__ float sigmoidf(float x) { return 1.0f / (1.0f + __expf(-x)); }

__device__ __forceinline__ void async16(const void* g, void* l) {
  __builtin_amdgcn_global_load_lds(
      (const __attribute__((address_space(1))) u32*)g,
      (__attribute__((address_space(3))) u32*)l, 16, 0, 0);
}

// ---------------------------------------------------------------------------
// prep: A fp32 -> bf16 in ws, and fp32 copy into output slot 1
// ---------------------------------------------------------------------------
__global__ __launch_bounds__(256) void prep_a(
    const float* __restrict__ A, u16* __restrict__ Abf, float* __restrict__ outA)
{
  const long i = ((long)blockIdx.x * 256 + threadIdx.x) * 4;
  float4 v = *(const float4*)(A + i);
  *(float4*)(outA + i) = v;
  ushort4 p;
  p.x = f2bf(v.x); p.y = f2bf(v.y); p.z = f2bf(v.z); p.w = f2bf(v.w);
  *(ushort4*)(Abf + i) = p;
}

// ---------------------------------------------------------------------------
// prep: build WcT [128][WK] bf16: rows 0..63 = (W0+W1)^T, 64..127 = W2^T,
// k = k3*CIN + cin, zero pad k >= 3*CIN. tw layout: [3][1][3][CIN][64]
// ---------------------------------------------------------------------------
__global__ __launch_bounds__(256) void prep_w(
    const float* __restrict__ tw, u16* __restrict__ WcT, int CIN, int WK)
{
  const int idx = blockIdx.x * 256 + threadIdx.x;
  if (idx >= 128 * WK) return;
  const int c = idx / WK;
  const int k = idx - c * WK;
  const int KR = CIN * 3;
  float v = 0.0f;
  if (k < KR) {
    const int k3 = k / CIN, cin = k - k3 * CIN;
    if (c < 64)
      v = tw[(k3 * CIN + cin) * 64 + c] + tw[(3 * CIN + k3 * CIN + cin) * 64 + c];
    else
      v = tw[(6 * CIN + k3 * CIN + cin) * 64 + (c - 64)];
  }
  WcT[idx] = f2bf(v);
}

// ---------------------------------------------------------------------------
// TB1 + theta1, full MFMA. x [16][2048][24][2] fp32. W1 [128][8] bf16 prepped.
// GEMM1: C1[c'][pos] = W'[c'][k]*patch[pos][k] (K=6 pad 32). Gate+relu in regs.
// LDS round-trip (wave-private, XOR granules) -> GEMM2 x theta1 (K=64,N=16).
// Output U1[(b*22+t)*16+p][n] bf16, packed b64 stores.
// Block: 256 pos = 256 n, one (b,t). Wave w: pos-tiles w*4..w*4+3.
// ---------------------------------------------------------------------------
__global__ __launch_bounds__(256) void tb1_kernel(
    const float* __restrict__ x, const u16* __restrict__ W1,
    const float* __restrict__ bias, const float* __restrict__ th1,
    u16* __restrict__ U1)
{
  __shared__ float Bts[64], Bgs[64];
  __shared__ u16 t2buf[4][16 * 64];
  const int tid = threadIdx.x;
  if (tid < 64) { Bts[tid] = bias[tid] + bias[64 + tid]; Bgs[tid] = bias[128 + tid]; }
  const int lane = tid & 63, w = tid >> 6;
  const int lm = lane & 15, q = lane >> 4;
  const int b = blockIdx.y, t = blockIdx.z;
  const int n0 = blockIdx.x * 256 + w * 64;

  // GEMM1 A-frags: weights (m=c'), q==0 lanes hold k=0..5
  s16x8 wfrag[8];
#pragma unroll
  for (int mt = 0; mt < 8; mt++) {
    wfrag[mt] = (s16x8){0, 0, 0, 0, 0, 0, 0, 0};
    if (q == 0) wfrag[mt] = *(const s16x8*)(W1 + (mt * 16 + lm) * 8);
  }
  // GEMM2 B-frags: theta1 (n=p=lm, k=c=q*8+j)
  s16x8 tfrag[2];
#pragma unroll
  for (int kk = 0; kk < 2; kk++)
#pragma unroll
    for (int j = 0; j < 8; j++)
      tfrag[kk][j] = (short)f2bf(th1[(kk * 32 + q * 8 + j) * 16 + lm]);

  // prefetch x patches for all 4 pos-tiles (q==0 lanes)
  float xv[4][6];
  if (q == 0) {
#pragma unroll
    for (int nt = 0; nt < 4; nt++) {
      const float* xp = x + ((long)(b * 2048 + n0 + nt * 16 + lm) * 24 + t) * 2;
#pragma unroll
      for (int j = 0; j < 6; j++) xv[nt][j] = xp[j];
    }
  }
  __syncthreads();
  // per-lane biases: c' = mt*16 + q*4 + r
  float bt4[4][4], bg4[4][4];
#pragma unroll
  for (int mt = 0; mt < 4; mt++)
#pragma unroll
    for (int r = 0; r < 4; r++) {
      bt4[mt][r] = Bts[mt * 16 + q * 4 + r];
      bg4[mt][r] = Bgs[mt * 16 + q * 4 + r];
    }

  u16* myt2 = t2buf[w];
  const long orowbase = (long)((b * 22 + t) * 16) << 11;

#pragma unroll
  for (int nt = 0; nt < 4; nt++) {
    s16x8 pfrag = (s16x8){0, 0, 0, 0, 0, 0, 0, 0};
    if (q == 0) {
#pragma unroll
      for (int j = 0; j < 6; j++) pfrag[j] = (short)f2bf(xv[nt][j]);
    }
    f32x4 acc1[8];
#pragma unroll
    for (int mt = 0; mt < 8; mt++) acc1[mt] = f32x4{0.f, 0.f, 0.f, 0.f};
#pragma unroll
    for (int mt = 0; mt < 8; mt++)
      acc1[mt] = __builtin_amdgcn_mfma_f32_16x16x32_bf16(wfrag[mt], pfrag, acc1[mt], 0, 0, 0);

    // gate + relu, write c-quads to wave-private LDS (XOR-swizzled granules)
#pragma unroll
    for (int mt = 0; mt < 4; mt++) {
      u32 pk[2];
      u16 pv[4];
#pragma unroll
      for (int r = 0; r < 4; r++) {
        const float temp = acc1[mt][r] + bt4[mt][r];
        const float ga = acc1[mt + 4][r] + bg4[mt][r];
        pv[r] = f2bf(fmaxf(temp * sigmoidf(ga), 0.0f));
      }
      pk[0] = (u32)pv[0] | ((u32)pv[1] << 16);
      pk[1] = (u32)pv[2] | ((u32)pv[3] << 16);
      // quad Q = mt*4+q; granule g=Q>>1, half=Q&1; phys = g ^ (lm&7)
      const int g = (mt * 4 + q) >> 1, half = q & 1;
      *(uint2*)(myt2 + lm * 64 + (g ^ (lm & 7)) * 8 + half * 4) = make_uint2(pk[0], pk[1]);
    }

    // GEMM2: A-frag from LDS (m=pos=lm, k=c), 2 K-tiles
    f32x4 acc2 = f32x4{0.f, 0.f, 0.f, 0.f};
#pragma unroll
    for (int kk = 0; kk < 2; kk++) {
      s16x8 af = *(const s16x8*)(myt2 + lm * 64 + ((kk * 4 + q) ^ (lm & 7)) * 8);
      acc2 = __builtin_amdgcn_mfma_f32_16x16x32_bf16(af, tfrag[kk], acc2, 0, 0, 0);
    }
    // store: lane (p=lm, pos=q*4+r) -> U1 row bt*16+p, cols n0+nt*16+q*4..+3
    u16 ov[4];
#pragma unroll
    for (int r = 0; r < 4; r++) ov[r] = f2bf(acc2[r]);
    *(uint2*)(U1 + orowbase + ((long)lm << 11) + n0 + nt * 16 + q * 4) =
        make_uint2((u32)ov[0] | ((u32)ov[1] << 16), (u32)ov[2] | ((u32)ov[3] << 16));
  }
}

// ---------------------------------------------------------------------------
// Spatial GEMM (NT): C[i,col] = sum_j A[i,j] * X[col, j]  (+ optional relu)
// ---------------------------------------------------------------------------
template <int RELU>
__global__ __launch_bounds__(256, 2) void sp_gemm(
    const u16* __restrict__ A, const u16* __restrict__ X,
    u16* __restrict__ C, int Ncols)
{
  __shared__ u16 ldsA[128 * 64];
  __shared__ u16 ldsB[128 * 64];
  const int lane = threadIdx.x & 63;
  const int w = threadIdx.x >> 6;

  const int ct = blockIdx.x >> 4;
  const int rt = blockIdx.x & 15;
  const int i0 = rt * 128;
  const int c0 = ct * 128;

  const int wm = w & 1, wn = w >> 1;
  const int lm = lane & 15, q = lane >> 4;

  f32x4 acc[4][4];
#pragma unroll
  for (int a = 0; a < 4; a++)
#pragma unroll
    for (int b2 = 0; b2 < 4; b2++) acc[a][b2] = f32x4{0.f, 0.f, 0.f, 0.f};

  const int srow = lane >> 3;
  const int sg = (lane & 7) ^ srow;
  const u16* gA = A + ((long)(i0 + w * 32 + srow) << 11) + sg * 8;
  const u16* gB = X + ((long)(c0 + w * 32 + srow) << 11) + sg * 8;
  u16* lA = ldsA + w * 2048;
  u16* lB = ldsB + w * 2048;

  for (int k0 = 0; k0 < 2048; k0 += 64) {
    __syncthreads();
#pragma unroll
    for (int j = 0; j < 4; j++) {
      async16(gA + j * 16384 + k0, lA + j * 512);
      async16(gB + j * 16384 + k0, lB + j * 512);
    }
    __syncthreads();
#pragma unroll
    for (int kk = 0; kk < 2; kk++) {
      const int ph = (kk * 4 + q) ^ (lm & 7);
      s16x8 af[4], bfr[4];
#pragma unroll
      for (int mt = 0; mt < 4; mt++)
        af[mt] = *(const s16x8*)(ldsA + (wm * 64 + mt * 16 + lm) * 64 + ph * 8);
#pragma unroll
      for (int nt = 0; nt < 4; nt++)
        bfr[nt] = *(const s16x8*)(ldsB + (wn * 64 + nt * 16 + lm) * 64 + ph * 8);
#pragma unroll
      for (int mt = 0; mt < 4; mt++)
#pragma unroll
        for (int nt = 0; nt < 4; nt++)
          acc[mt][nt] = __builtin_amdgcn_mfma_f32_16x16x32_bf16(af[mt], bfr[nt], acc[mt][nt], 0, 0, 0);
    }
  }

#pragma unroll
  for (int mt = 0; mt < 4; mt++) {
#pragma unroll
    for (int r = 0; r < 4; r++) {
      const long i = i0 + wm * 64 + mt * 16 + q * 4 + r;
      u16* crow = C + i * Ncols + c0 + wn * 64 + lm;
#pragma unroll
      for (int nt = 0; nt < 4; nt++) {
        float v = acc[mt][nt][r];
        if (RELU) v = fmaxf(v, 0.0f);
        crow[nt * 16] = f2bf(v);
      }
    }
  }
}

// ---------------------------------------------------------------------------
// theta2 + transpose, MFMA. in [n][16][TOUT][64] bf16 ->
// U2[(b*TOUT+t)*16+p][n], no relu. Block: 256 n x one (b,t).
// A-frag gathered b128 from global (row k-contiguous); B-frag = theta.
// ---------------------------------------------------------------------------
__global__ __launch_bounds__(256) void theta_t(
    const u16* __restrict__ in, const float* __restrict__ th,
    u16* __restrict__ outp, int TOUT)
{
  const int tid = threadIdx.x;
  const int lane = tid & 63, w = tid >> 6;
  const int lm = lane & 15, q = lane >> 4;
  const int bt = blockIdx.y;
  const int b = bt / TOUT, t = bt - b * TOUT;
  const int n0 = blockIdx.x * 256 + w * 64;

  s16x8 tfrag[2];
#pragma unroll
  for (int kk = 0; kk < 2; kk++)
#pragma unroll
    for (int j = 0; j < 8; j++)
      tfrag[kk][j] = (short)f2bf(th[(kk * 32 + q * 8 + j) * 16 + lm]);

  // prefetch A-frags for all 4 pos-tiles
  s16x8 af[4][2];
#pragma unroll
  for (int nt = 0; nt < 4; nt++) {
    const int n = n0 + nt * 16 + lm;
    const u16* rp = in + ((long)((n * 16 + b) * TOUT + t) << 6);
    af[nt][0] = *(const s16x8*)(rp + q * 8);
    af[nt][1] = *(const s16x8*)(rp + 32 + q * 8);
  }

  const long orowbase = (long)(bt * 16) << 11;
#pragma unroll
  for (int nt = 0; nt < 4; nt++) {
    f32x4 acc = f32x4{0.f, 0.f, 0.f, 0.f};
    acc = __builtin_amdgcn_mfma_f32_16x16x32_bf16(af[nt][0], tfrag[0], acc, 0, 0, 0);
    acc = __builtin_amdgcn_mfma_f32_16x16x32_bf16(af[nt][1], tfrag[1], acc, 0, 0, 0);
    u16 ov[4];
#pragma unroll
    for (int r = 0; r < 4; r++) ov[r] = f2bf(acc[r]);
    *(uint2*)(outp + orowbase + ((long)lm << 11) + n0 + nt * 16 + q * 4) =
        make_uint2((u32)ov[0] | ((u32)ov[1] << 16), (u32)ov[2] | ((u32)ov[3] << 16));
  }
}

// ---------------------------------------------------------------------------
// Conv temporal block as GEMM, register-resident weights.
// Input [n][16][TIN][CIN] bf16. Wave w: all 128 pos x couts {w*16..+16, +64}.
// Output [n][16][TOUT][64].
// ---------------------------------------------------------------------------
template <int CIN, int TIN, int MINW>
__global__ __launch_bounds__(256, MINW) void conv_gemm(
    const u16* __restrict__ in, const u16* __restrict__ WcT,
    const float* __restrict__ bias, u16* __restrict__ out)
{
  constexpr int WK = (CIN == 64) ? 192 : 64;
  constexpr int G = WK / 8;
  constexpr int KI = WK / 32;
  constexpr int TOUT = TIN - 2;
  constexpr int ROWS = 16 * TIN * CIN;
  constexpr int LDSE = (128 * WK > 128 * 72) ? 128 * WK : 128 * 72;
  __shared__ u16 lds[LDSE];

  const int tid = threadIdx.x;
  const int lane = tid & 63;
  const int w = tid >> 6;
  const int lm = lane & 15, q = lane >> 4;
  const int pos0 = blockIdx.x << 7;
  const int n0 = pos0 & 2047;
  const int bt = pos0 >> 11;
  const int b = bt / TOUT, t = bt - b * TOUT;
  const int cb = (b * TIN + t) * CIN;

#pragma unroll
  for (int j = 0; j < G / 2; j++) {
    const int Gi = (j * 4 + w) * 64 + lane;
    const int row = Gi / G;
    const int p = Gi - row * G;
    const int l = p ^ (row & 7);
    async16(in + (long)(n0 + row) * ROWS + cb + l * 8, lds + (j * 4 + w) * 512);
  }

  s16x8 wf[2][KI];
  {
    const u16* wp = WcT + (w * 16 + lm) * WK + q * 8;
#pragma unroll
    for (int kk = 0; kk < KI; kk++) {
      wf[0][kk] = *(const s16x8*)(wp + kk * 32);
      wf[1][kk] = *(const s16x8*)(wp + 64 * WK + kk * 32);
    }
  }

  f32x4 acc[8][2];
#pragma unroll
  for (int m = 0; m < 8; m++) {
    acc[m][0] = f32x4{0.f, 0.f, 0.f, 0.f};
    acc[m][1] = f32x4{0.f, 0.f, 0.f, 0.f};
  }

  __syncthreads();

#pragma unroll
  for (int kk = 0; kk < KI; kk++) {
    const int ph = (kk * 4 + q) ^ (lm & 7);
#pragma unroll
    for (int mt = 0; mt < 8; mt++) {
      s16x8 pf = *(const s16x8*)(lds + (mt * 16 + lm) * WK + ph * 8);
      acc[mt][0] = __builtin_amdgcn_mfma_f32_16x16x32_bf16(pf, wf[0][kk], acc[mt][0], 0, 0, 0);
      acc[mt][1] = __builtin_amdgcn_mfma_f32_16x16x32_bf16(pf, wf[1][kk], acc[mt][1], 0, 0, 0);
    }
  }

  __syncthreads();

  const int c = w * 16 + lm;
  const float bsum = bias[c] + bias[64 + c];
  const float bg = bias[128 + c];
#pragma unroll
  for (int mt = 0; mt < 8; mt++) {
#pragma unroll
    for (int r = 0; r < 4; r++) {
      const int pos = mt * 16 + q * 4 + r;
      const float temp = acc[mt][0][r] + bsum;
      const float ga = acc[mt][1][r] + bg;
      lds[pos * 72 + c] = f2bf(fmaxf(temp * sigmoidf(ga), 0.0f));
    }
  }
  __syncthreads();

  const int pos2 = tid >> 1, half = tid & 1;
  u16* orow = out + ((((long)(n0 + pos2) * 16 + b) * TOUT + t) << 6) + half * 32;
#pragma unroll
  for (int i = 0; i < 4; i++)
    *(uint4*)(orow + i * 8) = *(const uint4*)(lds + pos2 * 72 + half * 32 + i * 8);
}

// ---------------------------------------------------------------------------
// FC: out4[b][n][p] = sum_k out3row[k]*fw[k][p] + fb[p]; row = n*16+b, k=896
// ---------------------------------------------------------------------------
__global__ __launch_bounds__(256) void fc_kernel(
    const u16* __restrict__ o3, const float* __restrict__ fw,
    const float* __restrict__ fb, float* __restrict__ out)
{
  const int tid = threadIdx.x;
  const int r = blockIdx.x * 16 + (tid >> 4);
  const int p = tid & 15;
  const int pc = p < 12 ? p : 11;
  const int n = r >> 4, b = r & 15;
  const u16* rp = o3 + (long)r * 896;
  float acc = 0.0f;
  for (int k0 = 0; k0 < 896; k0 += 8) {
    s16x8 v = *(const s16x8*)(rp + k0);
#pragma unroll
    for (int j = 0; j < 8; j++) acc += bf2f_s(v[j]) * fw[(k0 + j) * 12 + pc];
  }
  if (p < 12) out[((long)b * 2048 + n) * 12 + p] = acc + fb[p];
}

// ---------------------------------------------------------------------------
extern "C" void kernel_launch(void* const* d_in, const int* in_sizes, int n_in,
                              void* d_out, int out_size, void* d_ws, size_t ws_size,
                              hipStream_t stream)
{
  const float* x    = (const float*)d_in[0];
  const float* A    = (const float*)d_in[1];
  const float* tb1w = (const float*)d_in[2];
  const float* tb1b = (const float*)d_in[3];
  const float* th1  = (const float*)d_in[4];
  const float* tb2w = (const float*)d_in[5];
  const float* tb2b = (const float*)d_in[6];
  const float* tb3w = (const float*)d_in[7];
  const float* tb3b = (const float*)d_in[8];
  const float* th2  = (const float*)d_in[9];
  const float* tb4w = (const float*)d_in[10];
  const float* tb4b = (const float*)d_in[11];
  const float* tb5w = (const float*)d_in[12];
  const float* tb5b = (const float*)d_in[13];
  const float* fw   = (const float*)d_in[14];
  const float* fb   = (const float*)d_in[15];
  float* out = (float*)d_out;

  char* ws = (char*)d_ws;
  u16* Abf  = (u16*)(ws + 0);            //  8,388,608 B
  u16* W2   = (u16*)(ws + 8388608);      //     16,384
  u16* W3   = (u16*)(ws + 8404992);      //     49,152
  u16* W4   = (u16*)(ws + 8454144);      //     16,384
  u16* W5   = (u16*)(ws + 8470528);      //     49,152
  u16* bufA = (u16*)(ws + 8519680);      // 92,274,688 (max live use 83.9 MB)
  u16* bufB = (u16*)(ws + 100794368);    // 92,274,688
  u16* W1   = (u16*)(ws + 8519680 + 88000000);  // 2 KB, in bufA tail slack

  prep_a<<<4096, 256, 0, stream>>>(A, Abf, out + 393216);
  prep_w<<<4, 256, 0, stream>>>(tb1w, W1, 2, 8);
  prep_w<<<32, 256, 0, stream>>>(tb2w, W2, 16, 64);
  prep_w<<<96, 256, 0, stream>>>(tb3w, W3, 64, 192);
  prep_w<<<32, 256, 0, stream>>>(tb4w, W4, 16, 64);
  prep_w<<<96, 256, 0, stream>>>(tb5w, W5, 64, 192);

  // ---- block 1:  U1 = TB1(x)*th1; t2 = relu(A*U1); TB2(t2)
  tb1_kernel<<<dim3(8, 16, 22), 256, 0, stream>>>(x, W1, tb1b, th1, bufA);
  sp_gemm<1><<<44 * 16, 256, 0, stream>>>(Abf, bufA, bufB, 5632);       // -> [n][16][22][16]
  conv_gemm<16, 22, 3><<<5120, 256, 0, stream>>>(bufB, W2, tb2b, bufA); // -> [n][16][20][64]
  // ---- block 2:  t = TB3(out1); U2 = t*th2; t2 = relu(A*U2); TB4(t2)
  conv_gemm<64, 20, 2><<<4608, 256, 0, stream>>>(bufA, W3, tb3b, bufB); // -> [n][16][18][64]
  theta_t<<<dim3(8, 288), 256, 0, stream>>>(bufB, th2, bufA, 18);       // -> U2 [(b,t,p)][n]
  sp_gemm<1><<<36 * 16, 256, 0, stream>>>(Abf, bufA, bufB, 4608);       // -> [n][16][18][16]
  conv_gemm<16, 18, 3><<<4096, 256, 0, stream>>>(bufB, W4, tb4b, bufA); // -> [n][16][16][64]
  // ---- tail
  conv_gemm<64, 16, 2><<<3584, 256, 0, stream>>>(bufA, W5, tb5b, bufB); // -> [n][16][14][64]
  fc_kernel<<<2048, 256, 0, stream>>>(bufB, fw, fb, out);
}

// Round 5
// 485.844 us; speedup vs baseline: 2.0838x; 1.1093x over previous
//
#include <hip/hip_runtime.h>

typedef unsigned short u16;
typedef unsigned int u32;
typedef __attribute__((ext_vector_type(4))) float f32x4;
typedef __attribute__((ext_vector_type(8))) short s16x8;

__device__ __forceinline__ u16 f2bf(float f) {
  union { float f; u32 u; } v; v.f = f;
  u32 u = v.u;
  return (u16)((u + 0x7fffu + ((u >> 16) & 1u)) >> 16);
}
__device__ __forceinline__ float bf2f(u16 b) {
  union { u32 u; float f; } v; v.u = ((u32)b) << 16;
  return v.f;
}
__device__ __forceinline__ float bf2f_s(short b) { return bf2f((u16)b); }
__device__ __forceinline__ float sigmoidf(float x) { return 1.0f / (1.0f + __expf(-x)); }

__device__ __forceinline__ void async16(const void* g, void* l) {
  __builtin_amdgcn_global_load_lds(
      (const __attribute__((address_space(1))) u32*)g,
      (__attribute__((address_space(3))) u32*)l, 16, 0, 0);
}

// ---------------------------------------------------------------------------
// prep: A fp32 -> bf16 in ws, and fp32 copy into output slot 1
// ---------------------------------------------------------------------------
__global__ __launch_bounds__(256) void prep_a(
    const float* __restrict__ A, u16* __restrict__ Abf, float* __restrict__ outA)
{
  const long i = ((long)blockIdx.x * 256 + threadIdx.x) * 4;
  float4 v = *(const float4*)(A + i);
  *(float4*)(outA + i) = v;
  ushort4 p;
  p.x = f2bf(v.x); p.y = f2bf(v.y); p.z = f2bf(v.z); p.w = f2bf(v.w);
  *(ushort4*)(Abf + i) = p;
}

// ---------------------------------------------------------------------------
// prep: build WcT [128][WK] bf16: rows 0..63 = (W0+W1)^T, 64..127 = W2^T,
// k = k3*CIN + cin, zero pad k >= 3*CIN. tw layout: [3][1][3][CIN][64]
// ---------------------------------------------------------------------------
__global__ __launch_bounds__(256) void prep_w(
    const float* __restrict__ tw, u16* __restrict__ WcT, int CIN, int WK)
{
  const int idx = blockIdx.x * 256 + threadIdx.x;
  if (idx >= 128 * WK) return;
  const int c = idx / WK;
  const int k = idx - c * WK;
  const int KR = CIN * 3;
  float v = 0.0f;
  if (k < KR) {
    const int k3 = k / CIN, cin = k - k3 * CIN;
    if (c < 64)
      v = tw[(k3 * CIN + cin) * 64 + c] + tw[(3 * CIN + k3 * CIN + cin) * 64 + c];
    else
      v = tw[(6 * CIN + k3 * CIN + cin) * 64 + (c - 64)];
  }
  WcT[idx] = f2bf(v);
}

// ---------------------------------------------------------------------------
// prep: fwT [16][896] bf16: fwT[p][k] = fw[k*12+p], zero for p >= 12
// ---------------------------------------------------------------------------
__global__ __launch_bounds__(256) void prep_fwt(
    const float* __restrict__ fw, u16* __restrict__ fwT)
{
  const int idx = blockIdx.x * 256 + threadIdx.x;
  if (idx >= 16 * 896) return;
  const int p = idx / 896;
  const int k = idx - p * 896;
  fwT[idx] = f2bf(p < 12 ? fw[k * 12 + p] : 0.0f);
}

// ---------------------------------------------------------------------------
// TB1 + theta1, full MFMA. x [16][2048][24][2] fp32. W1 [128][8] bf16 prepped.
// Output U1[(b*22+t)*16+p][n] bf16, packed b64 stores.
// ---------------------------------------------------------------------------
__global__ __launch_bounds__(256) void tb1_kernel(
    const float* __restrict__ x, const u16* __restrict__ W1,
    const float* __restrict__ bias, const float* __restrict__ th1,
    u16* __restrict__ U1)
{
  __shared__ float Bts[64], Bgs[64];
  __shared__ u16 t2buf[4][16 * 64];
  const int tid = threadIdx.x;
  if (tid < 64) { Bts[tid] = bias[tid] + bias[64 + tid]; Bgs[tid] = bias[128 + tid]; }
  const int lane = tid & 63, w = tid >> 6;
  const int lm = lane & 15, q = lane >> 4;
  const int b = blockIdx.y, t = blockIdx.z;
  const int n0 = blockIdx.x * 256 + w * 64;

  s16x8 wfrag[8];
#pragma unroll
  for (int mt = 0; mt < 8; mt++) {
    wfrag[mt] = (s16x8){0, 0, 0, 0, 0, 0, 0, 0};
    if (q == 0) wfrag[mt] = *(const s16x8*)(W1 + (mt * 16 + lm) * 8);
  }
  s16x8 tfrag[2];
#pragma unroll
  for (int kk = 0; kk < 2; kk++)
#pragma unroll
    for (int j = 0; j < 8; j++)
      tfrag[kk][j] = (short)f2bf(th1[(kk * 32 + q * 8 + j) * 16 + lm]);

  float xv[4][6];
  if (q == 0) {
#pragma unroll
    for (int nt = 0; nt < 4; nt++) {
      const float* xp = x + ((long)(b * 2048 + n0 + nt * 16 + lm) * 24 + t) * 2;
#pragma unroll
      for (int j = 0; j < 6; j++) xv[nt][j] = xp[j];
    }
  }
  __syncthreads();
  float bt4[4][4], bg4[4][4];
#pragma unroll
  for (int mt = 0; mt < 4; mt++)
#pragma unroll
    for (int r = 0; r < 4; r++) {
      bt4[mt][r] = Bts[mt * 16 + q * 4 + r];
      bg4[mt][r] = Bgs[mt * 16 + q * 4 + r];
    }

  u16* myt2 = t2buf[w];
  const long orowbase = (long)((b * 22 + t) * 16) << 11;

#pragma unroll
  for (int nt = 0; nt < 4; nt++) {
    s16x8 pfrag = (s16x8){0, 0, 0, 0, 0, 0, 0, 0};
    if (q == 0) {
#pragma unroll
      for (int j = 0; j < 6; j++) pfrag[j] = (short)f2bf(xv[nt][j]);
    }
    f32x4 acc1[8];
#pragma unroll
    for (int mt = 0; mt < 8; mt++) acc1[mt] = f32x4{0.f, 0.f, 0.f, 0.f};
#pragma unroll
    for (int mt = 0; mt < 8; mt++)
      acc1[mt] = __builtin_amdgcn_mfma_f32_16x16x32_bf16(wfrag[mt], pfrag, acc1[mt], 0, 0, 0);

#pragma unroll
    for (int mt = 0; mt < 4; mt++) {
      u32 pk[2];
      u16 pv[4];
#pragma unroll
      for (int r = 0; r < 4; r++) {
        const float temp = acc1[mt][r] + bt4[mt][r];
        const float ga = acc1[mt + 4][r] + bg4[mt][r];
        pv[r] = f2bf(fmaxf(temp * sigmoidf(ga), 0.0f));
      }
      pk[0] = (u32)pv[0] | ((u32)pv[1] << 16);
      pk[1] = (u32)pv[2] | ((u32)pv[3] << 16);
      const int g = (mt * 4 + q) >> 1, half = q & 1;
      *(uint2*)(myt2 + lm * 64 + (g ^ (lm & 7)) * 8 + half * 4) = make_uint2(pk[0], pk[1]);
    }

    f32x4 acc2 = f32x4{0.f, 0.f, 0.f, 0.f};
#pragma unroll
    for (int kk = 0; kk < 2; kk++) {
      s16x8 af = *(const s16x8*)(myt2 + lm * 64 + ((kk * 4 + q) ^ (lm & 7)) * 8);
      acc2 = __builtin_amdgcn_mfma_f32_16x16x32_bf16(af, tfrag[kk], acc2, 0, 0, 0);
    }
    u16 ov[4];
#pragma unroll
    for (int r = 0; r < 4; r++) ov[r] = f2bf(acc2[r]);
    *(uint2*)(U1 + orowbase + ((long)lm << 11) + n0 + nt * 16 + q * 4) =
        make_uint2((u32)ov[0] | ((u32)ov[1] << 16), (u32)ov[2] | ((u32)ov[3] << 16));
  }
}

// ---------------------------------------------------------------------------
// Spatial GEMM (NT): C[i,col] = sum_j A[i,j] * X[col, j]  (+ optional relu)
// ---------------------------------------------------------------------------
template <int RELU>
__global__ __launch_bounds__(256, 2) void sp_gemm(
    const u16* __restrict__ A, const u16* __restrict__ X,
    u16* __restrict__ C, int Ncols)
{
  __shared__ u16 ldsA[128 * 64];
  __shared__ u16 ldsB[128 * 64];
  const int lane = threadIdx.x & 63;
  const int w = threadIdx.x >> 6;

  const int ct = blockIdx.x >> 4;
  const int rt = blockIdx.x & 15;
  const int i0 = rt * 128;
  const int c0 = ct * 128;

  const int wm = w & 1, wn = w >> 1;
  const int lm = lane & 15, q = lane >> 4;

  f32x4 acc[4][4];
#pragma unroll
  for (int a = 0; a < 4; a++)
#pragma unroll
    for (int b2 = 0; b2 < 4; b2++) acc[a][b2] = f32x4{0.f, 0.f, 0.f, 0.f};

  const int srow = lane >> 3;
  const int sg = (lane & 7) ^ srow;
  const u16* gA = A + ((long)(i0 + w * 32 + srow) << 11) + sg * 8;
  const u16* gB = X + ((long)(c0 + w * 32 + srow) << 11) + sg * 8;
  u16* lA = ldsA + w * 2048;
  u16* lB = ldsB + w * 2048;

  for (int k0 = 0; k0 < 2048; k0 += 64) {
    __syncthreads();
#pragma unroll
    for (int j = 0; j < 4; j++) {
      async16(gA + j * 16384 + k0, lA + j * 512);
      async16(gB + j * 16384 + k0, lB + j * 512);
    }
    __syncthreads();
#pragma unroll
    for (int kk = 0; kk < 2; kk++) {
      const int ph = (kk * 4 + q) ^ (lm & 7);
      s16x8 af[4], bfr[4];
#pragma unroll
      for (int mt = 0; mt < 4; mt++)
        af[mt] = *(const s16x8*)(ldsA + (wm * 64 + mt * 16 + lm) * 64 + ph * 8);
#pragma unroll
      for (int nt = 0; nt < 4; nt++)
        bfr[nt] = *(const s16x8*)(ldsB + (wn * 64 + nt * 16 + lm) * 64 + ph * 8);
#pragma unroll
      for (int mt = 0; mt < 4; mt++)
#pragma unroll
        for (int nt = 0; nt < 4; nt++)
          acc[mt][nt] = __builtin_amdgcn_mfma_f32_16x16x32_bf16(af[mt], bfr[nt], acc[mt][nt], 0, 0, 0);
    }
  }

#pragma unroll
  for (int mt = 0; mt < 4; mt++) {
#pragma unroll
    for (int r = 0; r < 4; r++) {
      const long i = i0 + wm * 64 + mt * 16 + q * 4 + r;
      u16* crow = C + i * Ncols + c0 + wn * 64 + lm;
#pragma unroll
      for (int nt = 0; nt < 4; nt++) {
        float v = acc[mt][nt][r];
        if (RELU) v = fmaxf(v, 0.0f);
        crow[nt * 16] = f2bf(v);
      }
    }
  }
}

// ---------------------------------------------------------------------------
// theta2 + transpose, MFMA. in [n][16][TOUT][64] bf16 ->
// U2[(b*TOUT+t)*16+p][n], no relu.
// ---------------------------------------------------------------------------
__global__ __launch_bounds__(256) void theta_t(
    const u16* __restrict__ in, const float* __restrict__ th,
    u16* __restrict__ outp, int TOUT)
{
  const int tid = threadIdx.x;
  const int lane = tid & 63, w = tid >> 6;
  const int lm = lane & 15, q = lane >> 4;
  const int bt = blockIdx.y;
  const int b = bt / TOUT, t = bt - b * TOUT;
  const int n0 = blockIdx.x * 256 + w * 64;

  s16x8 tfrag[2];
#pragma unroll
  for (int kk = 0; kk < 2; kk++)
#pragma unroll
    for (int j = 0; j < 8; j++)
      tfrag[kk][j] = (short)f2bf(th[(kk * 32 + q * 8 + j) * 16 + lm]);

  s16x8 af[4][2];
#pragma unroll
  for (int nt = 0; nt < 4; nt++) {
    const int n = n0 + nt * 16 + lm;
    const u16* rp = in + ((long)((n * 16 + b) * TOUT + t) << 6);
    af[nt][0] = *(const s16x8*)(rp + q * 8);
    af[nt][1] = *(const s16x8*)(rp + 32 + q * 8);
  }

  const long orowbase = (long)(bt * 16) << 11;
#pragma unroll
  for (int nt = 0; nt < 4; nt++) {
    f32x4 acc = f32x4{0.f, 0.f, 0.f, 0.f};
    acc = __builtin_amdgcn_mfma_f32_16x16x32_bf16(af[nt][0], tfrag[0], acc, 0, 0, 0);
    acc = __builtin_amdgcn_mfma_f32_16x16x32_bf16(af[nt][1], tfrag[1], acc, 0, 0, 0);
    u16 ov[4];
#pragma unroll
    for (int r = 0; r < 4; r++) ov[r] = f2bf(acc[r]);
    *(uint2*)(outp + orowbase + ((long)lm << 11) + n0 + nt * 16 + q * 4) =
        make_uint2((u32)ov[0] | ((u32)ov[1] << 16), (u32)ov[2] | ((u32)ov[3] << 16));
  }
}

// ---------------------------------------------------------------------------
// Conv temporal block as GEMM, register-resident weights.
// Input [n][16][TIN][CIN] bf16. Wave w: all 128 pos x couts {w*16..+16, +64}.
// Output [n][16][TOUT][64].
// ---------------------------------------------------------------------------
template <int CIN, int TIN, int MINW>
__global__ __launch_bounds__(256, MINW) void conv_gemm(
    const u16* __restrict__ in, const u16* __restrict__ WcT,
    const float* __restrict__ bias, u16* __restrict__ out)
{
  constexpr int WK = (CIN == 64) ? 192 : 64;
  constexpr int G = WK / 8;
  constexpr int KI = WK / 32;
  constexpr int TOUT = TIN - 2;
  constexpr int ROWS = 16 * TIN * CIN;
  constexpr int LDSE = (128 * WK > 128 * 72) ? 128 * WK : 128 * 72;
  __shared__ u16 lds[LDSE];

  const int tid = threadIdx.x;
  const int lane = tid & 63;
  const int w = tid >> 6;
  const int lm = lane & 15, q = lane >> 4;
  const int pos0 = blockIdx.x << 7;
  const int n0 = pos0 & 2047;
  const int bt = pos0 >> 11;
  const int b = bt / TOUT, t = bt - b * TOUT;
  const int cb = (b * TIN + t) * CIN;

#pragma unroll
  for (int j = 0; j < G / 2; j++) {
    const int Gi = (j * 4 + w) * 64 + lane;
    const int row = Gi / G;
    const int p = Gi - row * G;
    const int l = p ^ (row & 7);
    async16(in + (long)(n0 + row) * ROWS + cb + l * 8, lds + (j * 4 + w) * 512);
  }

  s16x8 wf[2][KI];
  {
    const u16* wp = WcT + (w * 16 + lm) * WK + q * 8;
#pragma unroll
    for (int kk = 0; kk < KI; kk++) {
      wf[0][kk] = *(const s16x8*)(wp + kk * 32);
      wf[1][kk] = *(const s16x8*)(wp + 64 * WK + kk * 32);
    }
  }

  f32x4 acc[8][2];
#pragma unroll
  for (int m = 0; m < 8; m++) {
    acc[m][0] = f32x4{0.f, 0.f, 0.f, 0.f};
    acc[m][1] = f32x4{0.f, 0.f, 0.f, 0.f};
  }

  __syncthreads();

#pragma unroll
  for (int kk = 0; kk < KI; kk++) {
    const int ph = (kk * 4 + q) ^ (lm & 7);
#pragma unroll
    for (int mt = 0; mt < 8; mt++) {
      s16x8 pf = *(const s16x8*)(lds + (mt * 16 + lm) * WK + ph * 8);
      acc[mt][0] = __builtin_amdgcn_mfma_f32_16x16x32_bf16(pf, wf[0][kk], acc[mt][0], 0, 0, 0);
      acc[mt][1] = __builtin_amdgcn_mfma_f32_16x16x32_bf16(pf, wf[1][kk], acc[mt][1], 0, 0, 0);
    }
  }

  __syncthreads();

  const int c = w * 16 + lm;
  const float bsum = bias[c] + bias[64 + c];
  const float bg = bias[128 + c];
#pragma unroll
  for (int mt = 0; mt < 8; mt++) {
#pragma unroll
    for (int r = 0; r < 4; r++) {
      const int pos = mt * 16 + q * 4 + r;
      const float temp = acc[mt][0][r] + bsum;
      const float ga = acc[mt][1][r] + bg;
      lds[pos * 72 + c] = f2bf(fmaxf(temp * sigmoidf(ga), 0.0f));
    }
  }
  __syncthreads();

  const int pos2 = tid >> 1, half = tid & 1;
  u16* orow = out + ((((long)(n0 + pos2) * 16 + b) * TOUT + t) << 6) + half * 32;
#pragma unroll
  for (int i = 0; i < 4; i++)
    *(uint4*)(orow + i * 8) = *(const uint4*)(lds + pos2 * 72 + half * 32 + i * 8);
}

// ---------------------------------------------------------------------------
// FC via MFMA: out4[b][n][p] = sum_k o3[(n*16+b)][k] * fwT[p][k] + fb[p]
// M=32768 rows, K=896 (28 k-tiles), N=16 (12 used). 128 rows/block, 4 waves.
// fwT staged in LDS once; per k-tile: 2 global A-loads + 1 ds B-load + 2 MFMA.
// ---------------------------------------------------------------------------
__global__ __launch_bounds__(256) void fc_mfma(
    const u16* __restrict__ o3, const u16* __restrict__ fwT,
    const float* __restrict__ fb, float* __restrict__ out)
{
  __shared__ u16 sfw[16 * 896];
  const int tid = threadIdx.x;
#pragma unroll
  for (int i = 0; i < 7; i++)
    *(uint4*)(sfw + (i * 256 + tid) * 8) = *(const uint4*)(fwT + (i * 256 + tid) * 8);
  __syncthreads();

  const int lane = tid & 63, w = tid >> 6;
  const int lm = lane & 15, q = lane >> 4;
  const int row0 = blockIdx.x * 128 + w * 32;
  const u16* a0 = o3 + (long)(row0 + lm) * 896 + q * 8;
  const u16* bp = sfw + lm * 896 + q * 8;

  f32x4 acc0 = f32x4{0.f, 0.f, 0.f, 0.f};
  f32x4 acc1 = f32x4{0.f, 0.f, 0.f, 0.f};
#pragma unroll 7
  for (int kt = 0; kt < 28; kt++) {
    s16x8 af0 = *(const s16x8*)(a0 + kt * 32);
    s16x8 af1 = *(const s16x8*)(a0 + 16 * 896 + kt * 32);
    s16x8 bf = *(const s16x8*)(bp + kt * 32);
    acc0 = __builtin_amdgcn_mfma_f32_16x16x32_bf16(af0, bf, acc0, 0, 0, 0);
    acc1 = __builtin_amdgcn_mfma_f32_16x16x32_bf16(af1, bf, acc1, 0, 0, 0);
  }

  if (lm < 12) {
    const float bias = fb[lm];
#pragma unroll
    for (int r = 0; r < 4; r++) {
      const int row_a = row0 + q * 4 + r;
      out[((long)(row_a & 15) * 2048 + (row_a >> 4)) * 12 + lm] = acc0[r] + bias;
      const int row_b = row_a + 16;
      out[((long)(row_b & 15) * 2048 + (row_b >> 4)) * 12 + lm] = acc1[r] + bias;
    }
  }
}

// ---------------------------------------------------------------------------
extern "C" void kernel_launch(void* const* d_in, const int* in_sizes, int n_in,
                              void* d_out, int out_size, void* d_ws, size_t ws_size,
                              hipStream_t stream)
{
  const float* x    = (const float*)d_in[0];
  const float* A    = (const float*)d_in[1];
  const float* tb1w = (const float*)d_in[2];
  const float* tb1b = (const float*)d_in[3];
  const float* th1  = (const float*)d_in[4];
  const float* tb2w = (const float*)d_in[5];
  const float* tb2b = (const float*)d_in[6];
  const float* tb3w = (const float*)d_in[7];
  const float* tb3b = (const float*)d_in[8];
  const float* th2  = (const float*)d_in[9];
  const float* tb4w = (const float*)d_in[10];
  const float* tb4b = (const float*)d_in[11];
  const float* tb5w = (const float*)d_in[12];
  const float* tb5b = (const float*)d_in[13];
  const float* fw   = (const float*)d_in[14];
  const float* fb   = (const float*)d_in[15];
  float* out = (float*)d_out;

  char* ws = (char*)d_ws;
  u16* Abf  = (u16*)(ws + 0);            //  8,388,608 B
  u16* W2   = (u16*)(ws + 8388608);      //     16,384
  u16* W3   = (u16*)(ws + 8404992);      //     49,152
  u16* W4   = (u16*)(ws + 8454144);      //     16,384
  u16* W5   = (u16*)(ws + 8470528);      //     49,152
  u16* bufA = (u16*)(ws + 8519680);      // 92,274,688 (max live use 83.9 MB)
  u16* bufB = (u16*)(ws + 100794368);    // 92,274,688
  u16* W1   = (u16*)(ws + 8519680 + 88000000);  // 2 KB, in bufA tail slack
  u16* FWT  = (u16*)(ws + 8519680 + 88004096);  // 28,672 B, bufA tail slack

  prep_a<<<4096, 256, 0, stream>>>(A, Abf, out + 393216);
  prep_w<<<4, 256, 0, stream>>>(tb1w, W1, 2, 8);
  prep_w<<<32, 256, 0, stream>>>(tb2w, W2, 16, 64);
  prep_w<<<96, 256, 0, stream>>>(tb3w, W3, 64, 192);
  prep_w<<<32, 256, 0, stream>>>(tb4w, W4, 16, 64);
  prep_w<<<96, 256, 0, stream>>>(tb5w, W5, 64, 192);
  prep_fwt<<<56, 256, 0, stream>>>(fw, FWT);

  // ---- block 1:  U1 = TB1(x)*th1; t2 = relu(A*U1); TB2(t2)
  tb1_kernel<<<dim3(8, 16, 22), 256, 0, stream>>>(x, W1, tb1b, th1, bufA);
  sp_gemm<1><<<44 * 16, 256, 0, stream>>>(Abf, bufA, bufB, 5632);       // -> [n][16][22][16]
  conv_gemm<16, 22, 3><<<5120, 256, 0, stream>>>(bufB, W2, tb2b, bufA); // -> [n][16][20][64]
  // ---- block 2:  t = TB3(out1); U2 = t*th2; t2 = relu(A*U2); TB4(t2)
  conv_gemm<64, 20, 2><<<4608, 256, 0, stream>>>(bufA, W3, tb3b, bufB); // -> [n][16][18][64]
  theta_t<<<dim3(8, 288), 256, 0, stream>>>(bufB, th2, bufA, 18);       // -> U2 [(b,t,p)][n]
  sp_gemm<1><<<36 * 16, 256, 0, stream>>>(Abf, bufA, bufB, 4608);       // -> [n][16][18][16]
  conv_gemm<16, 18, 3><<<4096, 256, 0, stream>>>(bufB, W4, tb4b, bufA); // -> [n][16][16][64]
  // ---- tail
  conv_gemm<64, 16, 2><<<3584, 256, 0, stream>>>(bufA, W5, tb5b, bufB); // -> [n][16][14][64]
  fc_mfma<<<256, 256, 0, stream>>>(bufB, FWT, fb, out);
}

// Round 6
// 440.529 us; speedup vs baseline: 2.2982x; 1.1029x over previous
//
#include <hip/hip_runtime.h>

typedef unsigned short u16;
typedef unsigned int u32;
typedef __attribute__((ext_vector_type(4))) float f32x4;
typedef __attribute__((ext_vector_type(8))) short s16x8;

__device__ __forceinline__ u16 f2bf(float f) {
  union { float f; u32 u; } v; v.f = f;
  u32 u = v.u;
  return (u16)((u + 0x7fffu + ((u >> 16) & 1u)) >> 16);
}
__device__ __forceinline__ float bf2f(u16 b) {
  union { u32 u; float f; } v; v.u = ((u32)b) << 16;
  return v.f;
}
__device__ __forceinline__ float bf2f_s(short b) { return bf2f((u16)b); }
__device__ __forceinline__ float sigmoidf(float x) { return 1.0f / (1.0f + __expf(-x)); }

__device__ __forceinline__ void async16(const void* g, void* l) {
  __builtin_amdgcn_global_load_lds(
      (const __attribute__((address_space(1))) u32*)g,
      (__attribute__((address_space(3))) u32*)l, 16, 0, 0);
}

// ---------------------------------------------------------------------------
// prep: A fp32 -> bf16 in ws, and fp32 copy into output slot 1
// ---------------------------------------------------------------------------
__global__ __launch_bounds__(256) void prep_a(
    const float* __restrict__ A, u16* __restrict__ Abf, float* __restrict__ outA)
{
  const long i = ((long)blockIdx.x * 256 + threadIdx.x) * 4;
  float4 v = *(const float4*)(A + i);
  *(float4*)(outA + i) = v;
  ushort4 p;
  p.x = f2bf(v.x); p.y = f2bf(v.y); p.z = f2bf(v.z); p.w = f2bf(v.w);
  *(ushort4*)(Abf + i) = p;
}

// ---------------------------------------------------------------------------
// prep: build WcT [128][WK] bf16: rows 0..63 = (W0+W1)^T, 64..127 = W2^T,
// k = k3*CIN + cin, zero pad k >= 3*CIN. tw layout: [3][1][3][CIN][64]
// ---------------------------------------------------------------------------
__global__ __launch_bounds__(256) void prep_w(
    const float* __restrict__ tw, u16* __restrict__ WcT, int CIN, int WK)
{
  const int idx = blockIdx.x * 256 + threadIdx.x;
  if (idx >= 128 * WK) return;
  const int c = idx / WK;
  const int k = idx - c * WK;
  const int KR = CIN * 3;
  float v = 0.0f;
  if (k < KR) {
    const int k3 = k / CIN, cin = k - k3 * CIN;
    if (c < 64)
      v = tw[(k3 * CIN + cin) * 64 + c] + tw[(3 * CIN + k3 * CIN + cin) * 64 + c];
    else
      v = tw[(6 * CIN + k3 * CIN + cin) * 64 + (c - 64)];
  }
  WcT[idx] = f2bf(v);
}

// ---------------------------------------------------------------------------
// prep: fwT [16][896] bf16: fwT[p][k] = fw[k*12+p], zero for p >= 12
// ---------------------------------------------------------------------------
__global__ __launch_bounds__(256) void prep_fwt(
    const float* __restrict__ fw, u16* __restrict__ fwT)
{
  const int idx = blockIdx.x * 256 + threadIdx.x;
  if (idx >= 16 * 896) return;
  const int p = idx / 896;
  const int k = idx - p * 896;
  fwT[idx] = f2bf(p < 12 ? fw[k * 12 + p] : 0.0f);
}

// ---------------------------------------------------------------------------
// TB1 + theta1, full MFMA. x [16][2048][24][2] fp32. W1 [128][8] bf16 prepped.
// Output U1[(b*22+t)*16+p][n] bf16, packed b64 stores.
// ---------------------------------------------------------------------------
__global__ __launch_bounds__(256) void tb1_kernel(
    const float* __restrict__ x, const u16* __restrict__ W1,
    const float* __restrict__ bias, const float* __restrict__ th1,
    u16* __restrict__ U1)
{
  __shared__ float Bts[64], Bgs[64];
  __shared__ u16 t2buf[4][16 * 64];
  const int tid = threadIdx.x;
  if (tid < 64) { Bts[tid] = bias[tid] + bias[64 + tid]; Bgs[tid] = bias[128 + tid]; }
  const int lane = tid & 63, w = tid >> 6;
  const int lm = lane & 15, q = lane >> 4;
  const int b = blockIdx.y, t = blockIdx.z;
  const int n0 = blockIdx.x * 256 + w * 64;

  s16x8 wfrag[8];
#pragma unroll
  for (int mt = 0; mt < 8; mt++) {
    wfrag[mt] = (s16x8){0, 0, 0, 0, 0, 0, 0, 0};
    if (q == 0) wfrag[mt] = *(const s16x8*)(W1 + (mt * 16 + lm) * 8);
  }
  s16x8 tfrag[2];
#pragma unroll
  for (int kk = 0; kk < 2; kk++)
#pragma unroll
    for (int j = 0; j < 8; j++)
      tfrag[kk][j] = (short)f2bf(th1[(kk * 32 + q * 8 + j) * 16 + lm]);

  float xv[4][6];
  if (q == 0) {
#pragma unroll
    for (int nt = 0; nt < 4; nt++) {
      const float* xp = x + ((long)(b * 2048 + n0 + nt * 16 + lm) * 24 + t) * 2;
#pragma unroll
      for (int j = 0; j < 6; j++) xv[nt][j] = xp[j];
    }
  }
  __syncthreads();
  float bt4[4][4], bg4[4][4];
#pragma unroll
  for (int mt = 0; mt < 4; mt++)
#pragma unroll
    for (int r = 0; r < 4; r++) {
      bt4[mt][r] = Bts[mt * 16 + q * 4 + r];
      bg4[mt][r] = Bgs[mt * 16 + q * 4 + r];
    }

  u16* myt2 = t2buf[w];
  const long orowbase = (long)((b * 22 + t) * 16) << 11;

#pragma unroll
  for (int nt = 0; nt < 4; nt++) {
    s16x8 pfrag = (s16x8){0, 0, 0, 0, 0, 0, 0, 0};
    if (q == 0) {
#pragma unroll
      for (int j = 0; j < 6; j++) pfrag[j] = (short)f2bf(xv[nt][j]);
    }
    f32x4 acc1[8];
#pragma unroll
    for (int mt = 0; mt < 8; mt++) acc1[mt] = f32x4{0.f, 0.f, 0.f, 0.f};
#pragma unroll
    for (int mt = 0; mt < 8; mt++)
      acc1[mt] = __builtin_amdgcn_mfma_f32_16x16x32_bf16(wfrag[mt], pfrag, acc1[mt], 0, 0, 0);

#pragma unroll
    for (int mt = 0; mt < 4; mt++) {
      u32 pk[2];
      u16 pv[4];
#pragma unroll
      for (int r = 0; r < 4; r++) {
        const float temp = acc1[mt][r] + bt4[mt][r];
        const float ga = acc1[mt + 4][r] + bg4[mt][r];
        pv[r] = f2bf(fmaxf(temp * sigmoidf(ga), 0.0f));
      }
      pk[0] = (u32)pv[0] | ((u32)pv[1] << 16);
      pk[1] = (u32)pv[2] | ((u32)pv[3] << 16);
      const int g = (mt * 4 + q) >> 1, half = q & 1;
      *(uint2*)(myt2 + lm * 64 + (g ^ (lm & 7)) * 8 + half * 4) = make_uint2(pk[0], pk[1]);
    }

    f32x4 acc2 = f32x4{0.f, 0.f, 0.f, 0.f};
#pragma unroll
    for (int kk = 0; kk < 2; kk++) {
      s16x8 af = *(const s16x8*)(myt2 + lm * 64 + ((kk * 4 + q) ^ (lm & 7)) * 8);
      acc2 = __builtin_amdgcn_mfma_f32_16x16x32_bf16(af, tfrag[kk], acc2, 0, 0, 0);
    }
    u16 ov[4];
#pragma unroll
    for (int r = 0; r < 4; r++) ov[r] = f2bf(acc2[r]);
    *(uint2*)(U1 + orowbase + ((long)lm << 11) + n0 + nt * 16 + q * 4) =
        make_uint2((u32)ov[0] | ((u32)ov[1] << 16), (u32)ov[2] | ((u32)ov[3] << 16));
  }
}

// ---------------------------------------------------------------------------
// Spatial GEMM (NT): C[i,col] = sum_j A[i,j] * X[col, j]  (+ optional relu)
// ---------------------------------------------------------------------------
template <int RELU>
__global__ __launch_bounds__(256, 3) void sp_gemm(
    const u16* __restrict__ A, const u16* __restrict__ X,
    u16* __restrict__ C, int Ncols)
{
  __shared__ u16 ldsA[128 * 64];
  __shared__ u16 ldsB[128 * 64];
  const int lane = threadIdx.x & 63;
  const int w = threadIdx.x >> 6;

  const int ct = blockIdx.x >> 4;
  const int rt = blockIdx.x & 15;
  const int i0 = rt * 128;
  const int c0 = ct * 128;

  const int wm = w & 1, wn = w >> 1;
  const int lm = lane & 15, q = lane >> 4;

  f32x4 acc[4][4];
#pragma unroll
  for (int a = 0; a < 4; a++)
#pragma unroll
    for (int b2 = 0; b2 < 4; b2++) acc[a][b2] = f32x4{0.f, 0.f, 0.f, 0.f};

  const int srow = lane >> 3;
  const int sg = (lane & 7) ^ srow;
  const u16* gA = A + ((long)(i0 + w * 32 + srow) << 11) + sg * 8;
  const u16* gB = X + ((long)(c0 + w * 32 + srow) << 11) + sg * 8;
  u16* lA = ldsA + w * 2048;
  u16* lB = ldsB + w * 2048;

  for (int k0 = 0; k0 < 2048; k0 += 64) {
    __syncthreads();
#pragma unroll
    for (int j = 0; j < 4; j++) {
      async16(gA + j * 16384 + k0, lA + j * 512);
      async16(gB + j * 16384 + k0, lB + j * 512);
    }
    __syncthreads();
#pragma unroll
    for (int kk = 0; kk < 2; kk++) {
      const int ph = (kk * 4 + q) ^ (lm & 7);
      s16x8 af[4], bfr[4];
#pragma unroll
      for (int mt = 0; mt < 4; mt++)
        af[mt] = *(const s16x8*)(ldsA + (wm * 64 + mt * 16 + lm) * 64 + ph * 8);
#pragma unroll
      for (int nt = 0; nt < 4; nt++)
        bfr[nt] = *(const s16x8*)(ldsB + (wn * 64 + nt * 16 + lm) * 64 + ph * 8);
#pragma unroll
      for (int mt = 0; mt < 4; mt++)
#pragma unroll
        for (int nt = 0; nt < 4; nt++)
          acc[mt][nt] = __builtin_amdgcn_mfma_f32_16x16x32_bf16(af[mt], bfr[nt], acc[mt][nt], 0, 0, 0);
    }
  }

#pragma unroll
  for (int mt = 0; mt < 4; mt++) {
#pragma unroll
    for (int r = 0; r < 4; r++) {
      const long i = i0 + wm * 64 + mt * 16 + q * 4 + r;
      u16* crow = C + i * Ncols + c0 + wn * 64 + lm;
#pragma unroll
      for (int nt = 0; nt < 4; nt++) {
        float v = acc[mt][nt][r];
        if (RELU) v = fmaxf(v, 0.0f);
        crow[nt * 16] = f2bf(v);
      }
    }
  }
}

// ---------------------------------------------------------------------------
// Conv temporal block as GEMM, register-resident weights, segment-pipelined
// staging. Input [n][16][TIN][CIN] bf16. LDS patch layout [seg][128 rows][64],
// XOR-swizzled granules within each 64-elem segment row.
// Wave w: all 128 pos x couts {w*16..+16} (temps) + {64+w*16..} (gates).
// THETA==0: epilogue -> LDS(72) -> [n][16][TOUT][64] coalesced stores.
// THETA==1 (TB3): epilogue -> LDS(88) -> theta2 MFMA -> U2[(bt)*16+p][n].
// ---------------------------------------------------------------------------
template <int CIN, int TIN, int MINW, int THETA>
__global__ __launch_bounds__(256, MINW) void conv_gemm(
    const u16* __restrict__ in, const u16* __restrict__ WcT,
    const float* __restrict__ bias, const float* __restrict__ th,
    u16* __restrict__ out)
{
  constexpr int WK = (CIN == 64) ? 192 : 64;
  constexpr int KI = WK / 32;
  constexpr int NSEG = WK / 64;
  constexpr int TOUT = TIN - 2;
  constexpr int ROWS = 16 * TIN * CIN;
  constexpr int RST = THETA ? 88 : 72;
  constexpr int LDSE = (NSEG * 8192 > 128 * RST) ? NSEG * 8192 : 128 * RST;
  __shared__ u16 lds[LDSE];

  const int tid = threadIdx.x;
  const int lane = tid & 63;
  const int w = tid >> 6;
  const int lm = lane & 15, q = lane >> 4;
  const int pos0 = blockIdx.x << 7;
  const int n0 = pos0 & 2047;
  const int bt = pos0 >> 11;
  const int b = bt / TOUT, t = bt - b * TOUT;
  const int cb = (b * TIN + t) * CIN;

  const int srow_off = lane >> 3;            // row within 8-row group
  const int sgl = (lane & 7) ^ srow_off;     // swizzled granule in segment

  auto stage = [&](int s) {
#pragma unroll
    for (int i = 0; i < 4; i++) {
      const int row = i * 32 + w * 8 + srow_off;
      async16(in + (long)(n0 + row) * ROWS + cb + s * 64 + sgl * 8,
              lds + s * 8192 + (i * 32 + w * 8) * 64);
    }
  };

  stage(0);

  s16x8 wf[2][KI];
  {
    const u16* wp = WcT + (w * 16 + lm) * WK + q * 8;
#pragma unroll
    for (int kk = 0; kk < KI; kk++) {
      wf[0][kk] = *(const s16x8*)(wp + kk * 32);
      wf[1][kk] = *(const s16x8*)(wp + 64 * WK + kk * 32);
    }
  }
  s16x8 tfrag[2];
  if (THETA) {
#pragma unroll
    for (int kk = 0; kk < 2; kk++)
#pragma unroll
      for (int j = 0; j < 8; j++)
        tfrag[kk][j] = (short)f2bf(th[(kk * 32 + q * 8 + j) * 16 + lm]);
  }

  f32x4 acc[8][2];
#pragma unroll
  for (int m = 0; m < 8; m++) {
    acc[m][0] = f32x4{0.f, 0.f, 0.f, 0.f};
    acc[m][1] = f32x4{0.f, 0.f, 0.f, 0.f};
  }

  __syncthreads();                    // seg0 (+weights) ready
  if (NSEG == 3) stage(1);

  auto compute = [&](int kk) {
    const int s = kk >> 1;
    const int ph = (((kk & 1) * 4 + q) ^ (lm & 7));
#pragma unroll
    for (int mt = 0; mt < 8; mt++) {
      s16x8 pf = *(const s16x8*)(lds + s * 8192 + (mt * 16 + lm) * 64 + ph * 8);
      acc[mt][0] = __builtin_amdgcn_mfma_f32_16x16x32_bf16(pf, wf[0][kk], acc[mt][0], 0, 0, 0);
      acc[mt][1] = __builtin_amdgcn_mfma_f32_16x16x32_bf16(pf, wf[1][kk], acc[mt][1], 0, 0, 0);
    }
  };

  compute(0); compute(1);
  if (NSEG == 3) {
    __syncthreads();                  // seg1 ready (latency covered by kk0-1)
    stage(2);
    compute(2); compute(3);
    __syncthreads();                  // seg2 ready (covered by kk2-3)
    compute(4); compute(5);
  }

  __syncthreads();                    // all patch reads done; reuse LDS

  const int c = w * 16 + lm;
  const float bsum = bias[c] + bias[64 + c];
  const float bg = bias[128 + c];
#pragma unroll
  for (int mt = 0; mt < 8; mt++) {
#pragma unroll
    for (int r = 0; r < 4; r++) {
      const int pos = mt * 16 + q * 4 + r;
      const float temp = acc[mt][0][r] + bsum;
      const float ga = acc[mt][1][r] + bg;
      lds[pos * RST + c] = f2bf(fmaxf(temp * sigmoidf(ga), 0.0f));
    }
  }
  __syncthreads();

  if (THETA == 0) {
    const int pos2 = tid >> 1, half = tid & 1;
    u16* orow = out + ((((long)(n0 + pos2) * 16 + b) * TOUT + t) << 6) + half * 32;
#pragma unroll
    for (int i = 0; i < 4; i++)
      *(uint4*)(orow + i * 8) = *(const uint4*)(lds + pos2 * 72 + half * 32 + i * 8);
  } else {
    // theta2 GEMM: U2[bt*16+p][n] = sum_m res[pos][m] * th[m][p]
    const long orowbase = (long)(bt * 16) << 11;
#pragma unroll
    for (int mt2 = 0; mt2 < 2; mt2++) {
      const int prow = w * 32 + mt2 * 16 + lm;
      f32x4 a2 = f32x4{0.f, 0.f, 0.f, 0.f};
#pragma unroll
      for (int kk = 0; kk < 2; kk++) {
        s16x8 af = *(const s16x8*)(lds + prow * 88 + kk * 32 + q * 8);
        a2 = __builtin_amdgcn_mfma_f32_16x16x32_bf16(af, tfrag[kk], a2, 0, 0, 0);
      }
      u16 ov[4];
#pragma unroll
      for (int r = 0; r < 4; r++) ov[r] = f2bf(a2[r]);
      *(uint2*)(out + orowbase + ((long)lm << 11) + n0 + w * 32 + mt2 * 16 + q * 4) =
          make_uint2((u32)ov[0] | ((u32)ov[1] << 16), (u32)ov[2] | ((u32)ov[3] << 16));
    }
  }
}

// ---------------------------------------------------------------------------
// FC via MFMA: out4[b][n][p] = sum_k o3[(n*16+b)][k] * fwT[p][k] + fb[p]
// ---------------------------------------------------------------------------
__global__ __launch_bounds__(256) void fc_mfma(
    const u16* __restrict__ o3, const u16* __restrict__ fwT,
    const float* __restrict__ fb, float* __restrict__ out)
{
  __shared__ u16 sfw[16 * 896];
  const int tid = threadIdx.x;
#pragma unroll
  for (int i = 0; i < 7; i++)
    *(uint4*)(sfw + (i * 256 + tid) * 8) = *(const uint4*)(fwT + (i * 256 + tid) * 8);
  __syncthreads();

  const int lane = tid & 63, w = tid >> 6;
  const int lm = lane & 15, q = lane >> 4;
  const int row0 = blockIdx.x * 128 + w * 32;
  const u16* a0 = o3 + (long)(row0 + lm) * 896 + q * 8;
  const u16* bp = sfw + lm * 896 + q * 8;

  f32x4 acc0 = f32x4{0.f, 0.f, 0.f, 0.f};
  f32x4 acc1 = f32x4{0.f, 0.f, 0.f, 0.f};
#pragma unroll 7
  for (int kt = 0; kt < 28; kt++) {
    s16x8 af0 = *(const s16x8*)(a0 + kt * 32);
    s16x8 af1 = *(const s16x8*)(a0 + 16 * 896 + kt * 32);
    s16x8 bf = *(const s16x8*)(bp + kt * 32);
    acc0 = __builtin_amdgcn_mfma_f32_16x16x32_bf16(af0, bf, acc0, 0, 0, 0);
    acc1 = __builtin_amdgcn_mfma_f32_16x16x32_bf16(af1, bf, acc1, 0, 0, 0);
  }

  if (lm < 12) {
    const float bias = fb[lm];
#pragma unroll
    for (int r = 0; r < 4; r++) {
      const int row_a = row0 + q * 4 + r;
      out[((long)(row_a & 15) * 2048 + (row_a >> 4)) * 12 + lm] = acc0[r] + bias;
      const int row_b = row_a + 16;
      out[((long)(row_b & 15) * 2048 + (row_b >> 4)) * 12 + lm] = acc1[r] + bias;
    }
  }
}

// ---------------------------------------------------------------------------
extern "C" void kernel_launch(void* const* d_in, const int* in_sizes, int n_in,
                              void* d_out, int out_size, void* d_ws, size_t ws_size,
                              hipStream_t stream)
{
  const float* x    = (const float*)d_in[0];
  const float* A    = (const float*)d_in[1];
  const float* tb1w = (const float*)d_in[2];
  const float* tb1b = (const float*)d_in[3];
  const float* th1  = (const float*)d_in[4];
  const float* tb2w = (const float*)d_in[5];
  const float* tb2b = (const float*)d_in[6];
  const float* tb3w = (const float*)d_in[7];
  const float* tb3b = (const float*)d_in[8];
  const float* th2  = (const float*)d_in[9];
  const float* tb4w = (const float*)d_in[10];
  const float* tb4b = (const float*)d_in[11];
  const float* tb5w = (const float*)d_in[12];
  const float* tb5b = (const float*)d_in[13];
  const float* fw   = (const float*)d_in[14];
  const float* fb   = (const float*)d_in[15];
  float* out = (float*)d_out;

  char* ws = (char*)d_ws;
  u16* Abf  = (u16*)(ws + 0);            //  8,388,608 B
  u16* W2   = (u16*)(ws + 8388608);      //     16,384
  u16* W3   = (u16*)(ws + 8404992);      //     49,152
  u16* W4   = (u16*)(ws + 8454144);      //     16,384
  u16* W5   = (u16*)(ws + 8470528);      //     49,152
  u16* bufA = (u16*)(ws + 8519680);      // 92,274,688 (max live use 83.9 MB)
  u16* bufB = (u16*)(ws + 100794368);    // 92,274,688
  u16* W1   = (u16*)(ws + 8519680 + 88000000);  // 2 KB, in bufA tail slack
  u16* FWT  = (u16*)(ws + 8519680 + 88004096);  // 28,672 B, bufA tail slack

  prep_a<<<4096, 256, 0, stream>>>(A, Abf, out + 393216);
  prep_w<<<4, 256, 0, stream>>>(tb1w, W1, 2, 8);
  prep_w<<<32, 256, 0, stream>>>(tb2w, W2, 16, 64);
  prep_w<<<96, 256, 0, stream>>>(tb3w, W3, 64, 192);
  prep_w<<<32, 256, 0, stream>>>(tb4w, W4, 16, 64);
  prep_w<<<96, 256, 0, stream>>>(tb5w, W5, 64, 192);
  prep_fwt<<<56, 256, 0, stream>>>(fw, FWT);

  // ---- block 1:  U1 = TB1(x)*th1; t2 = relu(A*U1); out1 = TB2(t2)
  tb1_kernel<<<dim3(8, 16, 22), 256, 0, stream>>>(x, W1, tb1b, th1, bufA);
  sp_gemm<1><<<44 * 16, 256, 0, stream>>>(Abf, bufA, bufB, 5632);
  conv_gemm<16, 22, 3, 0><<<5120, 256, 0, stream>>>(bufB, W2, tb2b, nullptr, bufA); // -> [n][16][20][64]
  // ---- block 2:  U2 = TB3(out1)*th2 (fused); t2 = relu(A*U2); TB4(t2)
  conv_gemm<64, 20, 3, 1><<<4608, 256, 0, stream>>>(bufA, W3, tb3b, th2, bufB);     // -> U2 [(b,t,p)][n]
  sp_gemm<1><<<36 * 16, 256, 0, stream>>>(Abf, bufB, bufA, 4608);
  conv_gemm<16, 18, 3, 0><<<4096, 256, 0, stream>>>(bufA, W4, tb4b, nullptr, bufB); // -> [n][16][16][64]
  // ---- tail
  conv_gemm<64, 16, 3, 0><<<3584, 256, 0, stream>>>(bufB, W5, tb5b, nullptr, bufA); // -> [n][16][14][64]
  fc_mfma<<<256, 256, 0, stream>>>(bufA, FWT, fb, out);
}

// Round 7
// 432.119 us; speedup vs baseline: 2.3429x; 1.0195x over previous
//
#include <hip/hip_runtime.h>

typedef unsigned short u16;
typedef unsigned int u32;
typedef __attribute__((ext_vector_type(4))) float f32x4;
typedef __attribute__((ext_vector_type(8))) short s16x8;

__device__ __forceinline__ u16 f2bf(float f) {
  union { float f; u32 u; } v; v.f = f;
  u32 u = v.u;
  return (u16)((u + 0x7fffu + ((u >> 16) & 1u)) >> 16);
}
__device__ __forceinline__ float bf2f(u16 b) {
  union { u32 u; float f; } v; v.u = ((u32)b) << 16;
  return v.f;
}
__device__ __forceinline__ float bf2f_s(short b) { return bf2f((u16)b); }
__device__ __forceinline__ float sigmoidf(float x) { return 1.0f / (1.0f + __expf(-x)); }

__device__ __forceinline__ void async16(const void* g, void* l) {
  __builtin_amdgcn_global_load_lds(
      (const __attribute__((address_space(1))) u32*)g,
      (__attribute__((address_space(3))) u32*)l, 16, 0, 0);
}

// ---------------------------------------------------------------------------
// prep: A fp32 -> bf16 in ws, and fp32 copy into output slot 1
// ---------------------------------------------------------------------------
__global__ __launch_bounds__(256) void prep_a(
    const float* __restrict__ A, u16* __restrict__ Abf, float* __restrict__ outA)
{
  const long i = ((long)blockIdx.x * 256 + threadIdx.x) * 4;
  float4 v = *(const float4*)(A + i);
  *(float4*)(outA + i) = v;
  ushort4 p;
  p.x = f2bf(v.x); p.y = f2bf(v.y); p.z = f2bf(v.z); p.w = f2bf(v.w);
  *(ushort4*)(Abf + i) = p;
}

// ---------------------------------------------------------------------------
// prep: build WcT [128][WK] bf16: rows 0..63 = (W0+W1)^T, 64..127 = W2^T,
// k = k3*CIN + cin, zero pad k >= 3*CIN. tw layout: [3][1][3][CIN][64]
// ---------------------------------------------------------------------------
__global__ __launch_bounds__(256) void prep_w(
    const float* __restrict__ tw, u16* __restrict__ WcT, int CIN, int WK)
{
  const int idx = blockIdx.x * 256 + threadIdx.x;
  if (idx >= 128 * WK) return;
  const int c = idx / WK;
  const int k = idx - c * WK;
  const int KR = CIN * 3;
  float v = 0.0f;
  if (k < KR) {
    const int k3 = k / CIN, cin = k - k3 * CIN;
    if (c < 64)
      v = tw[(k3 * CIN + cin) * 64 + c] + tw[(3 * CIN + k3 * CIN + cin) * 64 + c];
    else
      v = tw[(6 * CIN + k3 * CIN + cin) * 64 + (c - 64)];
  }
  WcT[idx] = f2bf(v);
}

// ---------------------------------------------------------------------------
// prep: fwT [16][896] bf16: fwT[p][k] = fw[k*12+p], zero for p >= 12
// ---------------------------------------------------------------------------
__global__ __launch_bounds__(256) void prep_fwt(
    const float* __restrict__ fw, u16* __restrict__ fwT)
{
  const int idx = blockIdx.x * 256 + threadIdx.x;
  if (idx >= 16 * 896) return;
  const int p = idx / 896;
  const int k = idx - p * 896;
  fwT[idx] = f2bf(p < 12 ? fw[k * 12 + p] : 0.0f);
}

// ---------------------------------------------------------------------------
// TB1 + theta1, full MFMA. x [16][2048][24][2] fp32. W1 [128][8] bf16 prepped.
// Output U1[(b*22+t)*16+p][n] bf16, packed b64 stores.
// ---------------------------------------------------------------------------
__global__ __launch_bounds__(256) void tb1_kernel(
    const float* __restrict__ x, const u16* __restrict__ W1,
    const float* __restrict__ bias, const float* __restrict__ th1,
    u16* __restrict__ U1)
{
  __shared__ float Bts[64], Bgs[64];
  __shared__ u16 t2buf[4][16 * 64];
  const int tid = threadIdx.x;
  if (tid < 64) { Bts[tid] = bias[tid] + bias[64 + tid]; Bgs[tid] = bias[128 + tid]; }
  const int lane = tid & 63, w = tid >> 6;
  const int lm = lane & 15, q = lane >> 4;
  const int b = blockIdx.y, t = blockIdx.z;
  const int n0 = blockIdx.x * 256 + w * 64;

  s16x8 wfrag[8];
#pragma unroll
  for (int mt = 0; mt < 8; mt++) {
    wfrag[mt] = (s16x8){0, 0, 0, 0, 0, 0, 0, 0};
    if (q == 0) wfrag[mt] = *(const s16x8*)(W1 + (mt * 16 + lm) * 8);
  }
  s16x8 tfrag[2];
#pragma unroll
  for (int kk = 0; kk < 2; kk++)
#pragma unroll
    for (int j = 0; j < 8; j++)
      tfrag[kk][j] = (short)f2bf(th1[(kk * 32 + q * 8 + j) * 16 + lm]);

  float xv[4][6];
  if (q == 0) {
#pragma unroll
    for (int nt = 0; nt < 4; nt++) {
      const float* xp = x + ((long)(b * 2048 + n0 + nt * 16 + lm) * 24 + t) * 2;
#pragma unroll
      for (int j = 0; j < 6; j++) xv[nt][j] = xp[j];
    }
  }
  __syncthreads();
  float bt4[4][4], bg4[4][4];
#pragma unroll
  for (int mt = 0; mt < 4; mt++)
#pragma unroll
    for (int r = 0; r < 4; r++) {
      bt4[mt][r] = Bts[mt * 16 + q * 4 + r];
      bg4[mt][r] = Bgs[mt * 16 + q * 4 + r];
    }

  u16* myt2 = t2buf[w];
  const long orowbase = (long)((b * 22 + t) * 16) << 11;

#pragma unroll
  for (int nt = 0; nt < 4; nt++) {
    s16x8 pfrag = (s16x8){0, 0, 0, 0, 0, 0, 0, 0};
    if (q == 0) {
#pragma unroll
      for (int j = 0; j < 6; j++) pfrag[j] = (short)f2bf(xv[nt][j]);
    }
    f32x4 acc1[8];
#pragma unroll
    for (int mt = 0; mt < 8; mt++) acc1[mt] = f32x4{0.f, 0.f, 0.f, 0.f};
#pragma unroll
    for (int mt = 0; mt < 8; mt++)
      acc1[mt] = __builtin_amdgcn_mfma_f32_16x16x32_bf16(wfrag[mt], pfrag, acc1[mt], 0, 0, 0);

#pragma unroll
    for (int mt = 0; mt < 4; mt++) {
      u32 pk[2];
      u16 pv[4];
#pragma unroll
      for (int r = 0; r < 4; r++) {
        const float temp = acc1[mt][r] + bt4[mt][r];
        const float ga = acc1[mt + 4][r] + bg4[mt][r];
        pv[r] = f2bf(fmaxf(temp * sigmoidf(ga), 0.0f));
      }
      pk[0] = (u32)pv[0] | ((u32)pv[1] << 16);
      pk[1] = (u32)pv[2] | ((u32)pv[3] << 16);
      const int g = (mt * 4 + q) >> 1, half = q & 1;
      *(uint2*)(myt2 + lm * 64 + (g ^ (lm & 7)) * 8 + half * 4) = make_uint2(pk[0], pk[1]);
    }

    f32x4 acc2 = f32x4{0.f, 0.f, 0.f, 0.f};
#pragma unroll
    for (int kk = 0; kk < 2; kk++) {
      s16x8 af = *(const s16x8*)(myt2 + lm * 64 + ((kk * 4 + q) ^ (lm & 7)) * 8);
      acc2 = __builtin_amdgcn_mfma_f32_16x16x32_bf16(af, tfrag[kk], acc2, 0, 0, 0);
    }
    u16 ov[4];
#pragma unroll
    for (int r = 0; r < 4; r++) ov[r] = f2bf(acc2[r]);
    *(uint2*)(U1 + orowbase + ((long)lm << 11) + n0 + nt * 16 + q * 4) =
        make_uint2((u32)ov[0] | ((u32)ov[1] << 16), (u32)ov[2] | ((u32)ov[3] << 16));
  }
}

// ---------------------------------------------------------------------------
// Spatial GEMM (NT): C[i,col] = sum_j A[i,j] * X[col, j]  (+ optional relu)
// ---------------------------------------------------------------------------
template <int RELU>
__global__ __launch_bounds__(256, 3) void sp_gemm(
    const u16* __restrict__ A, const u16* __restrict__ X,
    u16* __restrict__ C, int Ncols)
{
  __shared__ u16 ldsA[128 * 64];
  __shared__ u16 ldsB[128 * 64];
  const int lane = threadIdx.x & 63;
  const int w = threadIdx.x >> 6;

  const int ct = blockIdx.x >> 4;
  const int rt = blockIdx.x & 15;
  const int i0 = rt * 128;
  const int c0 = ct * 128;

  const int wm = w & 1, wn = w >> 1;
  const int lm = lane & 15, q = lane >> 4;

  f32x4 acc[4][4];
#pragma unroll
  for (int a = 0; a < 4; a++)
#pragma unroll
    for (int b2 = 0; b2 < 4; b2++) acc[a][b2] = f32x4{0.f, 0.f, 0.f, 0.f};

  const int srow = lane >> 3;
  const int sg = (lane & 7) ^ srow;
  const u16* gA = A + ((long)(i0 + w * 32 + srow) << 11) + sg * 8;
  const u16* gB = X + ((long)(c0 + w * 32 + srow) << 11) + sg * 8;
  u16* lA = ldsA + w * 2048;
  u16* lB = ldsB + w * 2048;

  for (int k0 = 0; k0 < 2048; k0 += 64) {
    __syncthreads();
#pragma unroll
    for (int j = 0; j < 4; j++) {
      async16(gA + j * 16384 + k0, lA + j * 512);
      async16(gB + j * 16384 + k0, lB + j * 512);
    }
    __syncthreads();
#pragma unroll
    for (int kk = 0; kk < 2; kk++) {
      const int ph = (kk * 4 + q) ^ (lm & 7);
      s16x8 af[4], bfr[4];
#pragma unroll
      for (int mt = 0; mt < 4; mt++)
        af[mt] = *(const s16x8*)(ldsA + (wm * 64 + mt * 16 + lm) * 64 + ph * 8);
#pragma unroll
      for (int nt = 0; nt < 4; nt++)
        bfr[nt] = *(const s16x8*)(ldsB + (wn * 64 + nt * 16 + lm) * 64 + ph * 8);
#pragma unroll
      for (int mt = 0; mt < 4; mt++)
#pragma unroll
        for (int nt = 0; nt < 4; nt++)
          acc[mt][nt] = __builtin_amdgcn_mfma_f32_16x16x32_bf16(af[mt], bfr[nt], acc[mt][nt], 0, 0, 0);
    }
  }

#pragma unroll
  for (int mt = 0; mt < 4; mt++) {
#pragma unroll
    for (int r = 0; r < 4; r++) {
      const long i = i0 + wm * 64 + mt * 16 + q * 4 + r;
      u16* crow = C + i * Ncols + c0 + wn * 64 + lm;
#pragma unroll
      for (int nt = 0; nt < 4; nt++) {
        float v = acc[mt][nt][r];
        if (RELU) v = fmaxf(v, 0.0f);
        crow[nt * 16] = f2bf(v);
      }
    }
  }
}

// ---------------------------------------------------------------------------
// CIN=64 conv (WK=192), vmcnt-pipelined: all 3 segments in flight, raw
// s_barrier + hand-counted s_waitcnt (vmcnt FIFO retires in issue order;
// weights/theta/bias issued FIRST so waits 8/4/0 pick out seg 0/1/2).
// THETA==1 (TB3): fused theta2 epilogue -> U2[(bt)*16+p][n].
// THETA==0 (TB5): -> [n][16][TOUT][64].
// ---------------------------------------------------------------------------
template <int TIN, int THETA>
__global__ __launch_bounds__(256, 3) void conv192_k(
    const u16* __restrict__ in, const u16* __restrict__ WcT,
    const float* __restrict__ bias, const float* __restrict__ th,
    u16* __restrict__ out)
{
  constexpr int WK = 192;
  constexpr int KI = 6;
  constexpr int TOUT = TIN - 2;
  constexpr int ROWS = 16 * TIN * 64;
  constexpr int RST = THETA ? 88 : 72;
  __shared__ u16 lds[3 * 8192];

  const int tid = threadIdx.x;
  const int lane = tid & 63;
  const int w = tid >> 6;
  const int lm = lane & 15, q = lane >> 4;
  const int pos0 = blockIdx.x << 7;
  const int n0 = pos0 & 2047;
  const int bt = pos0 >> 11;
  const int b = bt / TOUT, t = bt - b * TOUT;
  const long cbase = (long)n0 * ROWS + (b * TIN + t) * 64;

  // ---- group 1: all non-stage global loads (retire before segments) ----
  s16x8 wf[2][KI];
  {
    const u16* wp = WcT + (w * 16 + lm) * WK + q * 8;
#pragma unroll
    for (int kk = 0; kk < KI; kk++) {
      wf[0][kk] = *(const s16x8*)(wp + kk * 32);
      wf[1][kk] = *(const s16x8*)(wp + 64 * WK + kk * 32);
    }
  }
  s16x8 tfrag[2];
  if (THETA) {
#pragma unroll
    for (int kk = 0; kk < 2; kk++)
#pragma unroll
      for (int j = 0; j < 8; j++)
        tfrag[kk][j] = (short)f2bf(th[(kk * 32 + q * 8 + j) * 16 + lm]);
  }
  const int c = w * 16 + lm;
  const float bsum = bias[c] + bias[64 + c];
  const float bg = bias[128 + c];

  // ---- group 2: segment staging, order-pinned ----
  const int srow_off = lane >> 3;
  const int sgl = (lane & 7) ^ srow_off;
  __builtin_amdgcn_sched_barrier(0);
#pragma unroll
  for (int s = 0; s < 3; s++) {
#pragma unroll
    for (int i = 0; i < 4; i++) {
      const int row = i * 32 + w * 8 + srow_off;
      async16(in + cbase + (long)row * ROWS + s * 64 + sgl * 8,
              lds + s * 8192 + (i * 32 + w * 8) * 64);
    }
    __builtin_amdgcn_sched_barrier(0);
  }

  f32x4 acc[8][2];
#pragma unroll
  for (int m = 0; m < 8; m++) {
    acc[m][0] = f32x4{0.f, 0.f, 0.f, 0.f};
    acc[m][1] = f32x4{0.f, 0.f, 0.f, 0.f};
  }

  auto compute = [&](int kk) {
    const int s = kk >> 1;
    const int ph = (((kk & 1) * 4 + q) ^ (lm & 7));
#pragma unroll
    for (int mt = 0; mt < 8; mt++) {
      s16x8 pf = *(const s16x8*)(lds + s * 8192 + (mt * 16 + lm) * 64 + ph * 8);
      acc[mt][0] = __builtin_amdgcn_mfma_f32_16x16x32_bf16(pf, wf[0][kk], acc[mt][0], 0, 0, 0);
      acc[mt][1] = __builtin_amdgcn_mfma_f32_16x16x32_bf16(pf, wf[1][kk], acc[mt][1], 0, 0, 0);
    }
  };

  asm volatile("s_waitcnt vmcnt(8)" ::: "memory");   // seg0 landed
  __builtin_amdgcn_s_barrier();
  compute(0); compute(1);
  asm volatile("s_waitcnt vmcnt(4)" ::: "memory");   // seg1 landed
  __builtin_amdgcn_s_barrier();
  compute(2); compute(3);
  asm volatile("s_waitcnt vmcnt(0)" ::: "memory");   // seg2 landed
  __builtin_amdgcn_s_barrier();
  compute(4); compute(5);

  __syncthreads();                    // all patch reads done; reuse LDS

#pragma unroll
  for (int mt = 0; mt < 8; mt++) {
#pragma unroll
    for (int r = 0; r < 4; r++) {
      const int pos = mt * 16 + q * 4 + r;
      const float temp = acc[mt][0][r] + bsum;
      const float ga = acc[mt][1][r] + bg;
      lds[pos * RST + c] = f2bf(fmaxf(temp * sigmoidf(ga), 0.0f));
    }
  }
  __syncthreads();

  if (THETA == 0) {
    const int pos2 = tid >> 1, half = tid & 1;
    u16* orow = out + ((((long)(n0 + pos2) * 16 + b) * TOUT + t) << 6) + half * 32;
#pragma unroll
    for (int i = 0; i < 4; i++)
      *(uint4*)(orow + i * 8) = *(const uint4*)(lds + pos2 * 72 + half * 32 + i * 8);
  } else {
    const long orowbase = (long)(bt * 16) << 11;
#pragma unroll
    for (int mt2 = 0; mt2 < 2; mt2++) {
      const int prow = w * 32 + mt2 * 16 + lm;
      f32x4 a2 = f32x4{0.f, 0.f, 0.f, 0.f};
#pragma unroll
      for (int kk = 0; kk < 2; kk++) {
        s16x8 af = *(const s16x8*)(lds + prow * 88 + kk * 32 + q * 8);
        a2 = __builtin_amdgcn_mfma_f32_16x16x32_bf16(af, tfrag[kk], a2, 0, 0, 0);
      }
      u16 ov[4];
#pragma unroll
      for (int r = 0; r < 4; r++) ov[r] = f2bf(a2[r]);
      *(uint2*)(out + orowbase + ((long)lm << 11) + n0 + w * 32 + mt2 * 16 + q * 4) =
          make_uint2((u32)ov[0] | ((u32)ov[1] << 16), (u32)ov[2] | ((u32)ov[3] << 16));
    }
  }
}

// ---------------------------------------------------------------------------
// CIN=16 conv (WK=64), DUO: one block = 2 consecutive bt, both staged up
// front; bt1's latency hidden behind bt0's compute+epilogue. Raw barriers
// keep bt1's loads in flight. Output [n][16][TOUT][64].
// ---------------------------------------------------------------------------
template <int TIN>
__global__ __launch_bounds__(256, 3) void conv64_duo(
    const u16* __restrict__ in, const u16* __restrict__ WcT,
    const float* __restrict__ bias, u16* __restrict__ out)
{
  constexpr int TOUT = TIN - 2;
  constexpr int ROWS = 16 * TIN * 16;
  __shared__ u16 lds[2 * 9216];

  const int tid = threadIdx.x;
  const int lane = tid & 63;
  const int w = tid >> 6;
  const int lm = lane & 15, q = lane >> 4;
  const int g = blockIdx.x;
  const int n0 = (g & 15) << 7;
  const int btp = g >> 4;

  // ---- group 1: weights + bias first ----
  s16x8 wf[2][2];
  {
    const u16* wp = WcT + (w * 16 + lm) * 64 + q * 8;
#pragma unroll
    for (int kk = 0; kk < 2; kk++) {
      wf[0][kk] = *(const s16x8*)(wp + kk * 32);
      wf[1][kk] = *(const s16x8*)(wp + 64 * 64 + kk * 32);
    }
  }
  const int c = w * 16 + lm;
  const float bsum = bias[c] + bias[64 + c];
  const float bg = bias[128 + c];

  // ---- group 2: stage bt0 then bt1 ----
  const int srow_off = lane >> 3;
  const int sgl = (lane & 7) ^ srow_off;
  int bs[2], ts[2];
  __builtin_amdgcn_sched_barrier(0);
#pragma unroll
  for (int h = 0; h < 2; h++) {
    const int bt = btp * 2 + h;
    const int b = bt / TOUT, t = bt - b * TOUT;
    bs[h] = b; ts[h] = t;
    const long cbase = (long)n0 * ROWS + (b * TIN + t) * 16;
#pragma unroll
    for (int i = 0; i < 4; i++) {
      const int row = i * 32 + w * 8 + srow_off;
      async16(in + cbase + (long)row * ROWS + sgl * 8,
              lds + h * 9216 + (i * 32 + w * 8) * 64);
    }
    __builtin_amdgcn_sched_barrier(0);
  }

#pragma unroll
  for (int h = 0; h < 2; h++) {
    if (h == 0) asm volatile("s_waitcnt vmcnt(4)" ::: "memory");  // bt0 landed
    else        asm volatile("s_waitcnt vmcnt(0)" ::: "memory");  // bt1 landed
    __builtin_amdgcn_s_barrier();

    f32x4 acc[8][2];
#pragma unroll
    for (int m = 0; m < 8; m++) {
      acc[m][0] = f32x4{0.f, 0.f, 0.f, 0.f};
      acc[m][1] = f32x4{0.f, 0.f, 0.f, 0.f};
    }
#pragma unroll
    for (int kk = 0; kk < 2; kk++) {
      const int ph = ((kk * 4 + q) ^ (lm & 7));
#pragma unroll
      for (int mt = 0; mt < 8; mt++) {
        s16x8 pf = *(const s16x8*)(lds + h * 9216 + (mt * 16 + lm) * 64 + ph * 8);
        acc[mt][0] = __builtin_amdgcn_mfma_f32_16x16x32_bf16(pf, wf[0][kk], acc[mt][0], 0, 0, 0);
        acc[mt][1] = __builtin_amdgcn_mfma_f32_16x16x32_bf16(pf, wf[1][kk], acc[mt][1], 0, 0, 0);
      }
    }
    __builtin_amdgcn_s_barrier();      // all waves done reading buf h

#pragma unroll
    for (int mt = 0; mt < 8; mt++) {
#pragma unroll
      for (int r = 0; r < 4; r++) {
        const int pos = mt * 16 + q * 4 + r;
        const float temp = acc[mt][0][r] + bsum;
        const float ga = acc[mt][1][r] + bg;
        lds[h * 9216 + pos * 72 + c] = f2bf(fmaxf(temp * sigmoidf(ga), 0.0f));
      }
    }
    asm volatile("s_waitcnt lgkmcnt(0)" ::: "memory");
    __builtin_amdgcn_s_barrier();      // transpose writes visible

    const int pos2 = tid >> 1, half = tid & 1;
    u16* orow = out + ((((long)(n0 + pos2) * 16 + bs[h]) * TOUT + ts[h]) << 6) + half * 32;
#pragma unroll
    for (int i = 0; i < 4; i++)
      *(uint4*)(orow + i * 8) = *(const uint4*)(lds + h * 9216 + pos2 * 72 + half * 32 + i * 8);
  }
}

// ---------------------------------------------------------------------------
// FC via MFMA: out4[b][n][p] = sum_k o3[(n*16+b)][k] * fwT[p][k] + fb[p]
// ---------------------------------------------------------------------------
__global__ __launch_bounds__(256) void fc_mfma(
    const u16* __restrict__ o3, const u16* __restrict__ fwT,
    const float* __restrict__ fb, float* __restrict__ out)
{
  __shared__ u16 sfw[16 * 896];
  const int tid = threadIdx.x;
#pragma unroll
  for (int i = 0; i < 7; i++)
    *(uint4*)(sfw + (i * 256 + tid) * 8) = *(const uint4*)(fwT + (i * 256 + tid) * 8);
  __syncthreads();

  const int lane = tid & 63, w = tid >> 6;
  const int lm = lane & 15, q = lane >> 4;
  const int row0 = blockIdx.x * 128 + w * 32;
  const u16* a0 = o3 + (long)(row0 + lm) * 896 + q * 8;
  const u16* bp = sfw + lm * 896 + q * 8;

  f32x4 acc0 = f32x4{0.f, 0.f, 0.f, 0.f};
  f32x4 acc1 = f32x4{0.f, 0.f, 0.f, 0.f};
#pragma unroll 7
  for (int kt = 0; kt < 28; kt++) {
    s16x8 af0 = *(const s16x8*)(a0 + kt * 32);
    s16x8 af1 = *(const s16x8*)(a0 + 16 * 896 + kt * 32);
    s16x8 bf = *(const s16x8*)(bp + kt * 32);
    acc0 = __builtin_amdgcn_mfma_f32_16x16x32_bf16(af0, bf, acc0, 0, 0, 0);
    acc1 = __builtin_amdgcn_mfma_f32_16x16x32_bf16(af1, bf, acc1, 0, 0, 0);
  }

  if (lm < 12) {
    const float bias = fb[lm];
#pragma unroll
    for (int r = 0; r < 4; r++) {
      const int row_a = row0 + q * 4 + r;
      out[((long)(row_a & 15) * 2048 + (row_a >> 4)) * 12 + lm] = acc0[r] + bias;
      const int row_b = row_a + 16;
      out[((long)(row_b & 15) * 2048 + (row_b >> 4)) * 12 + lm] = acc1[r] + bias;
    }
  }
}

// ---------------------------------------------------------------------------
extern "C" void kernel_launch(void* const* d_in, const int* in_sizes, int n_in,
                              void* d_out, int out_size, void* d_ws, size_t ws_size,
                              hipStream_t stream)
{
  const float* x    = (const float*)d_in[0];
  const float* A    = (const float*)d_in[1];
  const float* tb1w = (const float*)d_in[2];
  const float* tb1b = (const float*)d_in[3];
  const float* th1  = (const float*)d_in[4];
  const float* tb2w = (const float*)d_in[5];
  const float* tb2b = (const float*)d_in[6];
  const float* tb3w = (const float*)d_in[7];
  const float* tb3b = (const float*)d_in[8];
  const float* th2  = (const float*)d_in[9];
  const float* tb4w = (const float*)d_in[10];
  const float* tb4b = (const float*)d_in[11];
  const float* tb5w = (const float*)d_in[12];
  const float* tb5b = (const float*)d_in[13];
  const float* fw   = (const float*)d_in[14];
  const float* fb   = (const float*)d_in[15];
  float* out = (float*)d_out;

  char* ws = (char*)d_ws;
  u16* Abf  = (u16*)(ws + 0);            //  8,388,608 B
  u16* W2   = (u16*)(ws + 8388608);      //     16,384
  u16* W3   = (u16*)(ws + 8404992);      //     49,152
  u16* W4   = (u16*)(ws + 8454144);      //     16,384
  u16* W5   = (u16*)(ws + 8470528);      //     49,152
  u16* bufA = (u16*)(ws + 8519680);      // 92,274,688 (max live use 83.9 MB)
  u16* bufB = (u16*)(ws + 100794368);    // 92,274,688
  u16* W1   = (u16*)(ws + 8519680 + 88000000);  // 2 KB, in bufA tail slack
  u16* FWT  = (u16*)(ws + 8519680 + 88004096);  // 28,672 B, bufA tail slack

  prep_a<<<4096, 256, 0, stream>>>(A, Abf, out + 393216);
  prep_w<<<4, 256, 0, stream>>>(tb1w, W1, 2, 8);
  prep_w<<<32, 256, 0, stream>>>(tb2w, W2, 16, 64);
  prep_w<<<96, 256, 0, stream>>>(tb3w, W3, 64, 192);
  prep_w<<<32, 256, 0, stream>>>(tb4w, W4, 16, 64);
  prep_w<<<96, 256, 0, stream>>>(tb5w, W5, 64, 192);
  prep_fwt<<<56, 256, 0, stream>>>(fw, FWT);

  // ---- block 1:  U1 = TB1(x)*th1; t2 = relu(A*U1); out1 = TB2(t2)
  tb1_kernel<<<dim3(8, 16, 22), 256, 0, stream>>>(x, W1, tb1b, th1, bufA);
  sp_gemm<1><<<44 * 16, 256, 0, stream>>>(Abf, bufA, bufB, 5632);
  conv64_duo<22><<<2560, 256, 0, stream>>>(bufB, W2, tb2b, bufA);           // -> [n][16][20][64]
  // ---- block 2:  U2 = TB3(out1)*th2 (fused); t2 = relu(A*U2); TB4(t2)
  conv192_k<20, 1><<<4608, 256, 0, stream>>>(bufA, W3, tb3b, th2, bufB);    // -> U2 [(b,t,p)][n]
  sp_gemm<1><<<36 * 16, 256, 0, stream>>>(Abf, bufB, bufA, 4608);
  conv64_duo<18><<<2048, 256, 0, stream>>>(bufA, W4, tb4b, bufB);           // -> [n][16][16][64]
  // ---- tail
  conv192_k<16, 0><<<3584, 256, 0, stream>>>(bufB, W5, tb5b, nullptr, bufA); // -> [n][16][14][64]
  fc_mfma<<<256, 256, 0, stream>>>(bufA, FWT, fb, out);
}